// Round 6
// baseline (62014.142 us; speedup 1.0000x reference)
//
#include <hip/hip_runtime.h>
#include <math.h>
#include <stdio.h>

#ifndef JAX_PARTITIONABLE
#define JAX_PARTITIONABLE 1
#endif

namespace {

constexpr int B  = 512;
constexpr int S  = 256;
constexpr int E  = 256;
constexpr int H  = 512;
constexpr int V  = 32000;
constexpr int G3 = 3 * H;      // 1536
constexpr int VBLK = 64;       // v-tile (also the softmax chunk width)
constexpr int NCH  = V / VBLK; // 500 chunks
constexpr int NDMAX = 96;      // max non-drawn rows per step (mean<=47)

typedef __bf16 bf16x8 __attribute__((ext_vector_type(8)));
typedef float  f32x4  __attribute__((ext_vector_type(4)));
typedef unsigned u32x4 __attribute__((ext_vector_type(4)));

#define AST(p, v) __hip_atomic_store((p), (v), __ATOMIC_RELAXED, __HIP_MEMORY_SCOPE_AGENT)
#define ALD(p)    __hip_atomic_load((p), __ATOMIC_RELAXED, __HIP_MEMORY_SCOPE_AGENT)

// ---------------- Threefry-2x32, 20 rounds (bit-exact JAX) ----------------
__device__ __forceinline__ void tf2x32(unsigned k0, unsigned k1,
                                       unsigned x0, unsigned x1,
                                       unsigned& o0, unsigned& o1) {
  unsigned ks2 = k0 ^ k1 ^ 0x1BD11BDAu;
  x0 += k0; x1 += k1;
#define TFR(r) { x0 += x1; x1 = (x1 << (r)) | (x1 >> (32 - (r))); x1 ^= x0; }
  TFR(13) TFR(15) TFR(26) TFR(6)   x0 += k1;  x1 += ks2 + 1u;
  TFR(17) TFR(29) TFR(16) TFR(24)  x0 += ks2; x1 += k0 + 2u;
  TFR(13) TFR(15) TFR(26) TFR(6)   x0 += k0;  x1 += k1 + 3u;
  TFR(17) TFR(29) TFR(16) TFR(24)  x0 += k1;  x1 += ks2 + 4u;
  TFR(13) TFR(15) TFR(26) TFR(6)   x0 += ks2; x1 += k0 + 5u;
#undef TFR
  o0 = x0; o1 = x1;
}

__device__ __forceinline__ unsigned rbits(unsigned g0, unsigned g1,
                                          unsigned b, unsigned v) {
#if JAX_PARTITIONABLE
  unsigned y0, y1;
  tf2x32(g0, g1, 0u, b * (unsigned)V + v, y0, y1);
  return y0 ^ y1;
#else
  const unsigned N2 = (unsigned)(B/2) * (unsigned)V;
  unsigned ii = b * (unsigned)V + v;
  unsigned jj = (b < 256) ? ii : ii - N2;
  unsigned y0, y1;
  tf2x32(g0, g1, jj, N2 + jj, y0, y1);
  return (b < 256) ? y0 : y1;
#endif
}

__device__ __forceinline__ float u01_from_bits(unsigned bits) {
  return __uint_as_float(0x3f800000u | (bits >> 9)) - 1.0f;
}

__device__ __forceinline__ float gumbel_exact(unsigned bits) {
  float u = u01_from_bits(bits);
  if (u == 0.0f) u = 1.1754943508222875e-38f;
  float w = (float)(-log((double)u));
  return (float)(-log((double)w));
}

__device__ __forceinline__ float gumbel_fast(unsigned bits) {
  float u = u01_from_bits(bits);
  if (u == 0.0f) u = 1.1754943508222875e-38f;
  float w = -__logf(u);
  return -__logf(w);
}

__device__ __forceinline__ unsigned short f2bf(float f) {
  unsigned u = __float_as_uint(f);
  unsigned r = (u + 0x7fffu + ((u >> 16) & 1u)) >> 16;   // RNE, no NaN inputs
  return (unsigned short)r;
}

// fragment-major offset (in elements) for MFMA A/B operand layout:
// element (row, k) lives at [row>>4][k>>5][ (row&15) + 16*((k>>3)&3) ][ k&7 ]
__device__ __forceinline__ size_t frag_off(int row, int k, int kTiles) {
  return ((size_t)((row >> 4) * kTiles + (k >> 5)) * 64
          + (row & 15) + 16 * ((k >> 3) & 3)) * 8 + (k & 7);
}

// ---------------- init: per-step keys (+ counter reset each replay) ---------
__global__ void k_init_rng(unsigned* __restrict__ kq, unsigned* __restrict__ ke,
                           unsigned* __restrict__ ctrs) {
  int t = threadIdx.x;  // 256 threads, 1 block
  ctrs[t] = 0u;         // join counters zeroed every replay
  unsigned h0, h1, e0, e1, g0, g1;
#if JAX_PARTITIONABLE
  tf2x32(0u, 42u, 0u, (unsigned)t, h0, h1);
  tf2x32(h0, h1, 0u, 0u, e0, e1);
  tf2x32(h0, h1, 0u, 1u, g0, g1);
#else
  unsigned a0, a1, b0, b1;
  if (t < 128) {
    tf2x32(0u, 42u, (unsigned)(2*t),   (unsigned)(256+2*t), a0, a1);
    tf2x32(0u, 42u, (unsigned)(2*t+1), (unsigned)(257+2*t), b0, b1);
    h0 = a0; h1 = b0;
  } else {
    int j = 2*t - 256;
    tf2x32(0u, 42u, (unsigned)j,     (unsigned)(256+j), a0, a1);
    tf2x32(0u, 42u, (unsigned)(j+1), (unsigned)(257+j), b0, b1);
    h0 = a1; h1 = b1;
  }
  unsigned p0, p1, q0, q1;
  tf2x32(h0, h1, 0u, 2u, p0, p1);
  tf2x32(h0, h1, 1u, 3u, q0, q1);
  e0 = p0; e1 = q0; g0 = p1; g1 = q1;
#endif
  ke[2*t] = e0; ke[2*t+1] = e1;
  kq[2*t] = g0; kq[2*t+1] = g1;
}

// ---------------- init: epsilon-greedy draw mask ----------------
__global__ void k_init_draws(const unsigned* __restrict__ ke,
                             unsigned char* __restrict__ draws) {
  int t = blockIdx.x;      // 0..255
  int b = threadIdx.x;     // 0..511
  unsigned k0 = ke[2*t], k1 = ke[2*t+1];
  unsigned bits, y0, y1;
#if JAX_PARTITIONABLE
  tf2x32(k0, k1, 0u, (unsigned)b, y0, y1);
  bits = y0 ^ y1;
#else
  if (b < 256) { tf2x32(k0, k1, (unsigned)b,       (unsigned)(256+b), y0, y1); bits = y0; }
  else         { tf2x32(k0, k1, (unsigned)(b-256), (unsigned)b,       y0, y1); bits = y1; }
#endif
  float u   = u01_from_bits(bits);
  float tf  = (float)t;
  float ex  = expf(__fmul_rn(-4.0f, tf) / 10000.0f);
  float eps = __fadd_rn(0.05f, __fmul_rn(0.95f, ex));
  draws[t*B + b] = (eps >= u) ? 1 : 0;
}

// ---------------- init: non-drawn slot assignment ----------------
__global__ void k_init_nd(const unsigned char* __restrict__ draws,
                          int* __restrict__ nd_slot) {
  int t = blockIdx.x;
  if (threadIdx.x != 0) return;
  int cnt = 0;
  for (int b = 0; b < B; b++) {
    if (!draws[t*B + b] && cnt < NDMAX) nd_slot[t*B + b] = cnt++;
    else nd_slot[t*B + b] = -1;
  }
}

// ---------------- init: drawn-row samples for t=0 only ----------------------
__global__ __launch_bounds__(256) void k_pre_argmax(
    const unsigned* __restrict__ kq, const unsigned char* __restrict__ draws,
    int* __restrict__ pre) {
  const int job  = blockIdx.x * 4 + (threadIdx.x >> 6);   // [0, B) at grid=B/4
  const int lane = threadIdx.x & 63;
  const int t = job >> 9, b = job & (B - 1);
  if (!draws[t*B + b]) { if (lane == 0) pre[job] = -1; return; }
  const unsigned g0 = kq[2*t], g1 = kq[2*t+1];
  unsigned best = 0u; int bv = V;
  for (int v = lane; v < V; v += 64) {
    unsigned bits = rbits(g0, g1, (unsigned)b, (unsigned)v) >> 9;
    if (bits > best || (bits == best && v < bv)) { best = bits; bv = v; }
  }
#pragma unroll
  for (int m = 1; m < 64; m <<= 1) {
    unsigned ob = __shfl_xor(best, m, 64);
    int      ov = __shfl_xor(bv,   m, 64);
    if (ob > best || (ob == best && ov < bv)) { best = ob; bv = ov; }
  }
  if (lane == 0) pre[job] = bv;
}

// ---------------- init: h=0, x=embedding[0] ----------------
__global__ void k_init_state(const float* __restrict__ emb,
                             float* __restrict__ x, float* __restrict__ h) {
  int b = blockIdx.x, tid = threadIdx.x;  // 256 threads
  x[b*E + tid] = emb[tid];
  h[b*H + tid] = 0.0f;
  h[b*H + 256 + tid] = 0.0f;
}

// ---------------- init: w_out -> bf16 in MFMA-fragment-major layout ----------
__global__ void k_cast_w(const float* __restrict__ w,
                         unsigned short* __restrict__ w_sw) {
  int g = blockIdx.x*256 + threadIdx.x;   // [0, V*H/8)
  int v  = g >> 6;
  int k0 = (g & 63) * 8;
  const float* src = w + (size_t)v*H + k0;
  union { unsigned short s[8]; u32x4 vv; } u;
#pragma unroll
  for (int e = 0; e < 8; e++) u.s[e] = f2bf(src[e]);
  *(u32x4*)&w_sw[frag_off(v, k0, H/32)] = u.vv;
}

// ---------------- GRU math helpers (accumulation semantics FROZEN) ----------
__device__ __forceinline__ float sigm_acc(float v) {
  return (float)(1.0 / (1.0 + exp(-(double)v)));
}
__device__ __forceinline__ float tanh_acc(float v) {
  return (float)tanh((double)v);
}

// ---------------- GRU gate GEMMs + in-kernel GRU tail ------------------------
// GEMM identical to the verified R4 k_gates (bit-identical fmaf chains).
// gi/gh are published with agent-scope (sc1, cache-bypassing) atomic stores;
// each block then drains vmcnt and bumps its row-group counter (48 blocks per
// row-tile y: 24 xt x 2 z). The LAST arriver of the group reads gi/gh back via
// agent loads and runs the frozen GRU math for its 64 rows. No spinning ->
// deadlock impossible. h double-buffered (hin/hout).
__global__ __launch_bounds__(512) void k_gates(
    const float* __restrict__ x, const float* __restrict__ hin,
    const float* __restrict__ w_ih, const float* __restrict__ w_hh,
    const float* __restrict__ b_ih, const float* __restrict__ b_hh,
    float* __restrict__ gi, float* __restrict__ gh,
    float* __restrict__ hout, unsigned short* __restrict__ h_sw,
    unsigned* __restrict__ ctrs, int t) {
  const int z = blockIdx.z;
  const float* A    = z ? hin  : x;
  const float* W    = z ? w_hh : w_ih;
  const float* bias = z ? b_hh : b_ih;
  float*       C    = z ? gh   : gi;
  const int K       = z ? H    : E;

  __shared__ __align__(16) float As[16][68];
  __shared__ __align__(16) float Ws[16][68];
  __shared__ unsigned s_old;
  const int tid = threadIdx.x;             // 0..511
  const int tx = tid & 15, ty = tid >> 4;  // ty 0..31
  const int row0 = blockIdx.y * 64, col0 = blockIdx.x * 64;
  float acc[2][4] = {};
  for (int k0 = 0; k0 < K; k0 += 16) {
#pragma unroll
    for (int l = 0; l < 2; l++) {
      int idx = tid + l*512;
      int r = idx >> 4, kk = idx & 15;
      As[kk][r] = A[(row0 + r)*K + k0 + kk];
      Ws[kk][r] = W[(col0 + r)*K + k0 + kk];
    }
    __syncthreads();
#pragma unroll
    for (int kk = 0; kk < 16; kk++) {
      const float2 av = *(const float2*)&As[kk][ty*2];
      const float4 wv = *(const float4*)&Ws[kk][tx*4];
      const float a[2] = {av.x, av.y};
      const float w[4] = {wv.x, wv.y, wv.z, wv.w};
#pragma unroll
      for (int i = 0; i < 2; i++)
#pragma unroll
        for (int j = 0; j < 4; j++) acc[i][j] = fmaf(a[i], w[j], acc[i][j]);
    }
    __syncthreads();
  }
#pragma unroll
  for (int i = 0; i < 2; i++) {
    int r = row0 + ty*2 + i;
    int c = col0 + tx*4;
#pragma unroll
    for (int j = 0; j < 4; j++)
      AST(&C[(size_t)r*G3 + c + j], __fadd_rn(acc[i][j], bias[c + j]));
  }

  // ---- group join: last of the 48 blocks for this row-tile runs the GRU ----
  asm volatile("s_waitcnt vmcnt(0)" ::: "memory");
  __syncthreads();
  if (tid == 0)
    s_old = __hip_atomic_fetch_add(&ctrs[blockIdx.y * 16], 1u,
                                   __ATOMIC_RELAXED, __HIP_MEMORY_SCOPE_AGENT);
  __syncthreads();
  if (s_old != 48u * (unsigned)(t + 1) - 1u) return;

  // GRU for rows [row0, row0+64): math identical to the frozen k_gru_update.
  for (int el = tid; el < 64 * H; el += 512) {
    const int b = row0 + (el >> 9);
    const int j = el & (H - 1);
    float gir = ALD(&gi[(size_t)b*G3 + j]);
    float giz = ALD(&gi[(size_t)b*G3 + H + j]);
    float gin = ALD(&gi[(size_t)b*G3 + 2*H + j]);
    float ghr = ALD(&gh[(size_t)b*G3 + j]);
    float ghz = ALD(&gh[(size_t)b*G3 + H + j]);
    float ghn = ALD(&gh[(size_t)b*G3 + 2*H + j]);
    float r  = sigm_acc(__fadd_rn(gir, ghr));
    float zz = sigm_acc(__fadd_rn(giz, ghz));
    float nn = tanh_acc(__fadd_rn(gin, __fmul_rn(r, ghn)));
    float hv = hin[(size_t)b*H + j];
    float t1 = __fmul_rn(__fsub_rn(1.0f, zz), nn);
    float t2 = __fmul_rn(zz, hv);
    float hn = __fadd_rn(t1, t2);
    hout[(size_t)b*H + j] = hn;
    h_sw[frag_off(b, j, H/32)] = f2bf(hn);
  }
}

// ---------------- bf16 MFMA logits GEMM + in-kernel finish tails -------------
// Tile path identical to verified R4 (barrier-free register-double-buffered
// direct loads), except partials are published with agent-scope atomic stores.
// After publishing, each tile block bumps the join counter; the LAST 512
// arrivals each adopt one row b (by arrival rank), spin until all 1000 tiles
// are in (relaxed agent polls - no cache maintenance), then run the finish
// body with agent loads. Spinners <= 511 and __launch_bounds__(256,2)
// guarantees >= 512 co-resident blocks -> deadlock-free.
// Grid (512, 3): y==0 pre-argmax slab (early exit); y in {1,2} the 1000 tiles.
__global__ __launch_bounds__(256, 2) void k_mfma_logits(
    const unsigned short* __restrict__ h_sw,
    const unsigned short* __restrict__ w_sw,
    const float* __restrict__ b_out,
    const unsigned* __restrict__ kq,
    const unsigned char* __restrict__ draws,
    int* __restrict__ pre,               // full [S*B] table
    const int* __restrict__ nd_slot_t,   // nd_slot + t*B
    float* __restrict__ pmax, float* __restrict__ psum,
    float* __restrict__ plog,
    float* __restrict__ nd_keys, float* __restrict__ nd_kmax,
    const float* __restrict__ h, const float* __restrict__ w_out,
    const float* __restrict__ emb, float* __restrict__ x,
    float* __restrict__ out_samples, float* __restrict__ out_lps,
    unsigned* __restrict__ ctrs, int t) {
  const int tid  = threadIdx.x;
  __shared__ unsigned sb[4];
  __shared__ int      sv[4];
  __shared__ unsigned s_old;
  __shared__ float sA[256];
  __shared__ int   cand[160];
  __shared__ float cand_key[160], cand_lg[160];
  __shared__ int   ccnt;
  __shared__ int   s_samp;
  __shared__ float s_blog;

  if (blockIdx.y == 0) {
    // ---- pre-argmax slab: drawn-row sample for step t+1 (bit-exact) ----
    const int tn = t + 1;
    if (tn >= S) return;
    const int b = blockIdx.x;            // 0..511
    if (!draws[tn*B + b]) { if (tid == 0) pre[tn*B + b] = -1; return; }
    const unsigned g0 = kq[2*tn], g1 = kq[2*tn+1];
    unsigned best = 0u; int bv = V;
    for (int v = tid; v < V; v += 256) {
      unsigned bits = rbits(g0, g1, (unsigned)b, (unsigned)v) >> 9;
      if (bits > best || (bits == best && v < bv)) { best = bits; bv = v; }
    }
#pragma unroll
    for (int m = 1; m < 64; m <<= 1) {
      unsigned ob = __shfl_xor(best, m, 64);
      int      ov = __shfl_xor(bv,   m, 64);
      if (ob > best || (ob == best && ov < bv)) { best = ob; bv = ov; }
    }
    const int wv = tid >> 6;
    if ((tid & 63) == 0) { sb[wv] = best; sv[wv] = bv; }
    __syncthreads();
    if (tid == 0) {
      for (int i = 1; i < 4; i++) {
        unsigned ob = sb[i]; int ov = sv[i];
        if (ob > best || (ob == best && ov < bv)) { best = ob; bv = ov; }
      }
      pre[tn*B + b] = bv;
    }
    return;
  }

  // ---- GEMM tiles: XCD-chunked bijective swizzle over 1024 slots ----
  const int L  = (blockIdx.y - 1) * 512 + blockIdx.x;  // == hw linear id - 512
  const int wg = (L & 7) * 128 + (L >> 3);             // 128 contiguous wg/XCD
  if (wg >= 2*NCH) return;                             // 24 idle slots
  {
    const int vblk = wg >> 1;      // 0..499; 64 contiguous vblk per XCD = 4 MB
    const int bblk = wg & 1;       // both b-halves of a vblk on the same XCD
    const int* __restrict__ pre_t = pre + t*B;
    const int lane = tid & 63, w = tid >> 6;
    const int quad = lane >> 4, l15 = lane & 15;

    f32x4 acc[4][4] = {};

    const int mtBase = bblk*16 + w*4;   // h rowTile base for this wave
    const int ntBase = vblk*4;          // w rowTile base
    const unsigned short* hp = h_sw + (size_t)mtBase*16*512 + lane*8;
    const unsigned short* wp = w_sw + (size_t)ntBase*16*512 + lane*8;

    bf16x8 afc[4], bfc[4];
#pragma unroll
    for (int mt = 0; mt < 4; mt++)
      afc[mt] = __builtin_bit_cast(bf16x8, *(const u32x4*)(hp + (size_t)(mt*16)*512));
#pragma unroll
    for (int nt = 0; nt < 4; nt++)
      bfc[nt] = __builtin_bit_cast(bf16x8, *(const u32x4*)(wp + (size_t)(nt*16)*512));

#pragma unroll 1
    for (int kt = 0; kt < 15; kt++) {
      bf16x8 afn[4], bfn[4];
#pragma unroll
      for (int mt = 0; mt < 4; mt++)
        afn[mt] = __builtin_bit_cast(bf16x8,
            *(const u32x4*)(hp + (size_t)(mt*16 + kt + 1)*512));
#pragma unroll
      for (int nt = 0; nt < 4; nt++)
        bfn[nt] = __builtin_bit_cast(bf16x8,
            *(const u32x4*)(wp + (size_t)(nt*16 + kt + 1)*512));
#pragma unroll
      for (int mt = 0; mt < 4; mt++)
#pragma unroll
        for (int nt = 0; nt < 4; nt++)
          acc[mt][nt] = __builtin_amdgcn_mfma_f32_16x16x32_bf16(
              afc[mt], bfc[nt], acc[mt][nt], 0, 0, 0);
#pragma unroll
      for (int mt = 0; mt < 4; mt++) afc[mt] = afn[mt];
#pragma unroll
      for (int nt = 0; nt < 4; nt++) bfc[nt] = bfn[nt];
    }
    {  // kt = 15
#pragma unroll
      for (int mt = 0; mt < 4; mt++)
#pragma unroll
        for (int nt = 0; nt < 4; nt++)
          acc[mt][nt] = __builtin_amdgcn_mfma_f32_16x16x32_bf16(
              afc[mt], bfc[nt], acc[mt][nt], 0, 0, 0);
    }

    // epilogue: publish partials with agent-scope atomic stores
    const int bW = bblk*256 + w*64;
    const int vW = vblk*64;
    const unsigned g0 = kq[2*t], g1 = kq[2*t+1];
    float bias[4];
#pragma unroll
    for (int nt = 0; nt < 4; nt++) bias[nt] = b_out[vW + nt*16 + l15];

#pragma unroll
    for (int mt = 0; mt < 4; mt++) {
#pragma unroll
      for (int r = 0; r < 4; r++) {
        const int b = bW + mt*16 + quad*4 + r;
        float lg[4];
#pragma unroll
        for (int nt = 0; nt < 4; nt++) lg[nt] = acc[mt][nt][r] + bias[nt];
        float lmax = fmaxf(fmaxf(lg[0], lg[1]), fmaxf(lg[2], lg[3]));
#pragma unroll
        for (int m = 1; m < 16; m <<= 1) lmax = fmaxf(lmax, __shfl_xor(lmax, m, 64));
        float ls = 0.0f;
#pragma unroll
        for (int nt = 0; nt < 4; nt++) ls += __expf(lg[nt] - lmax);
#pragma unroll
        for (int m = 1; m < 16; m <<= 1) ls += __shfl_xor(ls, m, 64);
        if (l15 == 0) {
          AST(&pmax[b*NCH + vblk], lmax);
          AST(&psum[b*NCH + vblk], ls);
        }
        const int pr = pre_t[b];
        if (pr >= 0) {
          int rel = pr - vW;
          if (rel >= 0 && rel < 64 && (rel & 15) == l15)
            AST(&plog[b], lg[rel >> 4]);
        } else {
          const int slot = nd_slot_t[b];
          if (slot >= 0) {
            float key[4];
#pragma unroll
            for (int nt = 0; nt < 4; nt++)
              key[nt] = lg[nt] + gumbel_fast(
                  rbits(g0, g1, (unsigned)b, (unsigned)(vW + nt*16 + l15)));
            float* dst = nd_keys + (size_t)slot*V + vW + l15;
#pragma unroll
            for (int nt = 0; nt < 4; nt++) AST(&dst[nt*16], key[nt]);
            float kmx = fmaxf(fmaxf(key[0], key[1]), fmaxf(key[2], key[3]));
#pragma unroll
            for (int m = 1; m < 16; m <<= 1) kmx = fmaxf(kmx, __shfl_xor(kmx, m, 64));
            if (l15 == 0) AST(&nd_kmax[slot*NCH + vblk], kmx);
          }
        }
      }
    }
  }

  // ---- join: bump counter; last 512 arrivals become per-row finishers ----
  asm volatile("s_waitcnt vmcnt(0)" ::: "memory");
  __syncthreads();
  if (tid == 0)
    s_old = __hip_atomic_fetch_add(&ctrs[128], 1u,
                                   __ATOMIC_RELAXED, __HIP_MEMORY_SCOPE_AGENT);
  __syncthreads();
  const unsigned base = 1000u * (unsigned)t;
  if (s_old < base + 488u) return;       // early arrivals free their slots
  const int fb = (int)(s_old - (base + 488u));   // adopted row, 0..511
  if (tid == 0) {
    while (__hip_atomic_load(&ctrs[128], __ATOMIC_RELAXED,
                             __HIP_MEMORY_SCOPE_AGENT) < base + 1000u)
      __builtin_amdgcn_s_sleep(2);
  }
  __syncthreads();

  // ================= finish for row fb (frozen k_finish body) ==============
  {
    const int b = fb;
    const int* pre_t    = pre + t*B;

    float m = -INFINITY;
    for (int c = tid; c < NCH; c += 256) m = fmaxf(m, ALD(&pmax[b*NCH + c]));
    sA[tid] = m; __syncthreads();
    for (int s = 128; s > 0; s >>= 1) {
      if (tid < s) sA[tid] = fmaxf(sA[tid], sA[tid+s]);
      __syncthreads();
    }
    const float M = sA[0];
    __syncthreads();
    float sum = 0.0f;
    for (int c = tid; c < NCH; c += 256)
      sum += ALD(&psum[b*NCH + c]) * expf(ALD(&pmax[b*NCH + c]) - M);
    sA[tid] = sum; __syncthreads();
    for (int s = 128; s > 0; s >>= 1) {
      if (tid < s) sA[tid] += sA[tid+s];
      __syncthreads();
    }
    const float SUM = sA[0];
    __syncthreads();

    const int pr = pre_t[b];             // block-uniform
    if (pr >= 0) {
      if (tid == 0) { s_samp = pr; s_blog = ALD(&plog[b]); }
    } else {
      const int slot = nd_slot_t[b];
      if (slot < 0) {                    // statistically impossible guard
        if (tid == 0) { s_samp = 0; s_blog = ALD(&plog[b]); }
      } else {
        const unsigned g0 = kq[2*t], g1 = kq[2*t+1];
        if (tid == 0) ccnt = 0;
        float km = -INFINITY;
        for (int c = tid; c < NCH; c += 256)
          km = fmaxf(km, ALD(&nd_kmax[slot*NCH + c]));
        sA[tid] = km; __syncthreads();
        for (int s = 128; s > 0; s >>= 1) {
          if (tid < s) sA[tid] = fmaxf(sA[tid], sA[tid+s]);
          __syncthreads();
        }
        const float thr = sA[0] - 0.0859375f;  // >= 2*(bf16 + fastlog err)
        __syncthreads();
        float* keys = nd_keys + (size_t)slot*V;
        for (int c = tid; c < NCH; c += 256) {
          if (ALD(&nd_kmax[slot*NCH + c]) >= thr) {
            for (int j = 0; j < VBLK; j++) {
              float k = ALD(&keys[c*VBLK + j]);
              if (k >= thr) {
                int p = atomicAdd(&ccnt, 1);
                if (p < 160) cand[p] = c*VBLK + j;
              }
            }
          }
        }
        __syncthreads();
        const int nc = min(ccnt, 160);
        const int wid = tid >> 6, lane = tid & 63;
        for (int c = wid; c < nc; c += 4) {
          const int v = cand[c];
          const float* wr = w_out + (size_t)v*H;
          const float* hr = h + (size_t)b*H;
          float s = 0.0f;
#pragma unroll
          for (int i = 0; i < 8; i++) s = fmaf(hr[lane + 64*i], wr[lane + 64*i], s);
#pragma unroll
          for (int mm = 1; mm < 64; mm <<= 1) s += __shfl_xor(s, mm, 64);
          if (lane == 0) {
            float logit = __fadd_rn(s, b_out[v]);
            float key   = __fadd_rn(logit,
                            gumbel_exact(rbits(g0, g1, (unsigned)b, (unsigned)v)));
            cand_key[c] = key; cand_lg[c] = logit;
          }
        }
        __syncthreads();
        if (tid == 0) {
          float bk = -INFINITY; int bv = V; float bl = 0.0f;
          for (int c = 0; c < nc; c++) {
            float k = cand_key[c]; int v = cand[c];
            if (k > bk || (k == bk && v < bv)) { bk = k; bv = v; bl = cand_lg[c]; }
          }
          s_samp = bv; s_blog = bl;
        }
      }
    }
    __syncthreads();
    const int sampled = s_samp;
    if (tid == 0) {
      float lse = (float)log((double)SUM);
      float lp  = __fsub_rn(__fsub_rn(s_blog, M), lse);
      out_samples[b*S + t] = (float)sampled;
      out_lps[b*S + t]     = lp;
    }
    x[b*E + tid] = emb[sampled*E + tid];
  }
}

} // namespace

extern "C" void kernel_launch(void* const* d_in, const int* in_sizes, int n_in,
                              void* d_out, int out_size, void* d_ws, size_t ws_size,
                              hipStream_t stream) {
  (void)in_sizes; (void)n_in; (void)out_size;
  const float* emb   = (const float*)d_in[0];
  const float* w_ih  = (const float*)d_in[1];
  const float* w_hh  = (const float*)d_in[2];
  const float* b_ih  = (const float*)d_in[3];
  const float* b_hh  = (const float*)d_in[4];
  const float* w_out = (const float*)d_in[5];
  const float* b_out = (const float*)d_in[6];
  float* out = (float*)d_out;

  char* wsb = (char*)d_ws;
  size_t off = 0;
  auto alloc = [&](size_t nbytes) {
    char* p = wsb + off;
    off += (nbytes + 255) & ~size_t(255);
    return p;
  };
  float* h0    = (float*)alloc((size_t)B*H*4);
  float* h1    = (float*)alloc((size_t)B*H*4);
  float* x     = (float*)alloc((size_t)B*E*4);
  float* gi    = (float*)alloc((size_t)B*G3*4);
  float* gh    = (float*)alloc((size_t)B*G3*4);
  unsigned short* h_sw = (unsigned short*)alloc((size_t)B*H*2);
  unsigned short* w_sw = (unsigned short*)alloc((size_t)V*H*2);
  float* pmax  = (float*)alloc((size_t)B*NCH*4);
  float* psum  = (float*)alloc((size_t)B*NCH*4);
  float* plog  = (float*)alloc((size_t)B*4);
  unsigned* kq = (unsigned*)alloc((size_t)S*2*4);
  unsigned* ke = (unsigned*)alloc((size_t)S*2*4);
  unsigned char* draws = (unsigned char*)alloc((size_t)S*B);
  int* pre     = (int*)alloc((size_t)S*B*4);
  int* nd_slot = (int*)alloc((size_t)S*B*4);
  float* nd_keys = (float*)alloc((size_t)NDMAX*V*4);
  float* nd_kmax = (float*)alloc((size_t)NDMAX*NCH*4);
  unsigned* ctrs = (unsigned*)alloc(256*4);
  if (off > ws_size) {
    fprintf(stderr, "kernel_launch: workspace too small (need %zu, have %zu)\n",
            off, ws_size);
    return;
  }

  k_init_rng<<<1, S, 0, stream>>>(kq, ke, ctrs);
  k_init_draws<<<S, B, 0, stream>>>(ke, draws);
  k_init_nd<<<S, 64, 0, stream>>>(draws, nd_slot);
  k_pre_argmax<<<B/4, 256, 0, stream>>>(kq, draws, pre);   // t=0 only
  k_init_state<<<B, 256, 0, stream>>>(emb, x, h0);
  k_cast_w<<<(V*H/8)/256, 256, 0, stream>>>(w_out, w_sw);

  for (int t = 0; t < S; t++) {
    float* hin  = (t & 1) ? h1 : h0;
    float* hout = (t & 1) ? h0 : h1;
    k_gates<<<dim3(G3/64, B/64, 2), 512, 0, stream>>>(
        x, hin, w_ih, w_hh, b_ih, b_hh, gi, gh, hout, h_sw, ctrs, t);
    k_mfma_logits<<<dim3(512, 3), 256, 0, stream>>>(
        h_sw, w_sw, b_out, kq, draws, pre, nd_slot + t*B,
        pmax, psum, plog, nd_keys, nd_kmax,
        hout, w_out, emb, x, out, out + (size_t)B*S, ctrs, t);
  }
}

// Round 7
// 36727.206 us; speedup vs baseline: 1.6885x; 1.6885x over previous
//
#include <hip/hip_runtime.h>
#include <math.h>
#include <stdio.h>

#ifndef JAX_PARTITIONABLE
#define JAX_PARTITIONABLE 1
#endif

namespace {

constexpr int B  = 512;
constexpr int S  = 256;
constexpr int E  = 256;
constexpr int H  = 512;
constexpr int V  = 32000;
constexpr int VBLK = 64;       // v-tile (also the softmax chunk width)
constexpr int NCH  = V / VBLK; // 500 chunks
constexpr int NDMAX = 96;      // max non-drawn rows per step (mean<=47)

typedef __bf16 bf16x8 __attribute__((ext_vector_type(8)));
typedef float  f32x4  __attribute__((ext_vector_type(4)));
typedef unsigned u32x4 __attribute__((ext_vector_type(4)));

// ---------------- Threefry-2x32, 20 rounds (bit-exact JAX) ----------------
__device__ __forceinline__ void tf2x32(unsigned k0, unsigned k1,
                                       unsigned x0, unsigned x1,
                                       unsigned& o0, unsigned& o1) {
  unsigned ks2 = k0 ^ k1 ^ 0x1BD11BDAu;
  x0 += k0; x1 += k1;
#define TFR(r) { x0 += x1; x1 = (x1 << (r)) | (x1 >> (32 - (r))); x1 ^= x0; }
  TFR(13) TFR(15) TFR(26) TFR(6)   x0 += k1;  x1 += ks2 + 1u;
  TFR(17) TFR(29) TFR(16) TFR(24)  x0 += ks2; x1 += k0 + 2u;
  TFR(13) TFR(15) TFR(26) TFR(6)   x0 += k0;  x1 += k1 + 3u;
  TFR(17) TFR(29) TFR(16) TFR(24)  x0 += k1;  x1 += ks2 + 4u;
  TFR(13) TFR(15) TFR(26) TFR(6)   x0 += ks2; x1 += k0 + 5u;
#undef TFR
  o0 = x0; o1 = x1;
}

__device__ __forceinline__ unsigned rbits(unsigned g0, unsigned g1,
                                          unsigned b, unsigned v) {
#if JAX_PARTITIONABLE
  unsigned y0, y1;
  tf2x32(g0, g1, 0u, b * (unsigned)V + v, y0, y1);
  return y0 ^ y1;
#else
  const unsigned N2 = (unsigned)(B/2) * (unsigned)V;
  unsigned ii = b * (unsigned)V + v;
  unsigned jj = (b < 256) ? ii : ii - N2;
  unsigned y0, y1;
  tf2x32(g0, g1, jj, N2 + jj, y0, y1);
  return (b < 256) ? y0 : y1;
#endif
}

__device__ __forceinline__ float u01_from_bits(unsigned bits) {
  return __uint_as_float(0x3f800000u | (bits >> 9)) - 1.0f;
}

__device__ __forceinline__ float gumbel_exact(unsigned bits) {
  float u = u01_from_bits(bits);
  if (u == 0.0f) u = 1.1754943508222875e-38f;
  float w = (float)(-log((double)u));
  return (float)(-log((double)w));
}

__device__ __forceinline__ float gumbel_fast(unsigned bits) {
  float u = u01_from_bits(bits);
  if (u == 0.0f) u = 1.1754943508222875e-38f;
  float w = -__logf(u);
  return -__logf(w);
}

__device__ __forceinline__ unsigned short f2bf(float f) {
  unsigned u = __float_as_uint(f);
  unsigned r = (u + 0x7fffu + ((u >> 16) & 1u)) >> 16;   // RNE, no NaN inputs
  return (unsigned short)r;
}

// fragment-major offset (in elements) for MFMA A/B operand layout:
// element (row, k) lives at [row>>4][k>>5][ (row&15) + 16*((k>>3)&3) ][ k&7 ]
__device__ __forceinline__ size_t frag_off(int row, int k, int kTiles) {
  return ((size_t)((row >> 4) * kTiles + (k >> 5)) * 64
          + (row & 15) + 16 * ((k >> 3) & 3)) * 8 + (k & 7);
}

// ---------------- init: per-step keys ----------------
__global__ void k_init_rng(unsigned* __restrict__ kq, unsigned* __restrict__ ke) {
  int t = threadIdx.x;  // 256 threads, 1 block
  unsigned h0, h1, e0, e1, g0, g1;
#if JAX_PARTITIONABLE
  tf2x32(0u, 42u, 0u, (unsigned)t, h0, h1);
  tf2x32(h0, h1, 0u, 0u, e0, e1);
  tf2x32(h0, h1, 0u, 1u, g0, g1);
#else
  unsigned a0, a1, b0, b1;
  if (t < 128) {
    tf2x32(0u, 42u, (unsigned)(2*t),   (unsigned)(256+2*t), a0, a1);
    tf2x32(0u, 42u, (unsigned)(2*t+1), (unsigned)(257+2*t), b0, b1);
    h0 = a0; h1 = b0;
  } else {
    int j = 2*t - 256;
    tf2x32(0u, 42u, (unsigned)j,     (unsigned)(256+j), a0, a1);
    tf2x32(0u, 42u, (unsigned)(j+1), (unsigned)(257+j), b0, b1);
    h0 = a1; h1 = b1;
  }
  unsigned p0, p1, q0, q1;
  tf2x32(h0, h1, 0u, 2u, p0, p1);
  tf2x32(h0, h1, 1u, 3u, q0, q1);
  e0 = p0; e1 = q0; g0 = p1; g1 = q1;
#endif
  ke[2*t] = e0; ke[2*t+1] = e1;
  kq[2*t] = g0; kq[2*t+1] = g1;
}

// ---------------- init: epsilon-greedy draw mask ----------------
__global__ void k_init_draws(const unsigned* __restrict__ ke,
                             unsigned char* __restrict__ draws) {
  int t = blockIdx.x;      // 0..255
  int b = threadIdx.x;     // 0..511
  unsigned k0 = ke[2*t], k1 = ke[2*t+1];
  unsigned bits, y0, y1;
#if JAX_PARTITIONABLE
  tf2x32(k0, k1, 0u, (unsigned)b, y0, y1);
  bits = y0 ^ y1;
#else
  if (b < 256) { tf2x32(k0, k1, (unsigned)b,       (unsigned)(256+b), y0, y1); bits = y0; }
  else         { tf2x32(k0, k1, (unsigned)(b-256), (unsigned)b,       y0, y1); bits = y1; }
#endif
  float u   = u01_from_bits(bits);
  float tf  = (float)t;
  float ex  = expf(__fmul_rn(-4.0f, tf) / 10000.0f);
  float eps = __fadd_rn(0.05f, __fmul_rn(0.95f, ex));
  draws[t*B + b] = (eps >= u) ? 1 : 0;
}

// ---------------- init: non-drawn slot assignment ----------------
__global__ void k_init_nd(const unsigned char* __restrict__ draws,
                          int* __restrict__ nd_slot) {
  int t = blockIdx.x;
  if (threadIdx.x != 0) return;
  int cnt = 0;
  for (int b = 0; b < B; b++) {
    if (!draws[t*B + b] && cnt < NDMAX) nd_slot[t*B + b] = cnt++;
    else nd_slot[t*B + b] = -1;
  }
}

// ---------------- init: drawn-row samples for t=0 only ----------------------
// (steady-state pre[t+1] is co-scheduled inside k_mfma_logits step t)
__global__ __launch_bounds__(256) void k_pre_argmax(
    const unsigned* __restrict__ kq, const unsigned char* __restrict__ draws,
    int* __restrict__ pre) {
  const int job  = blockIdx.x * 4 + (threadIdx.x >> 6);   // [0, B) at grid=B/4
  const int lane = threadIdx.x & 63;
  const int t = job >> 9, b = job & (B - 1);
  if (!draws[t*B + b]) { if (lane == 0) pre[job] = -1; return; }
  const unsigned g0 = kq[2*t], g1 = kq[2*t+1];
  unsigned best = 0u; int bv = V;
  for (int v = lane; v < V; v += 64) {
    unsigned bits = rbits(g0, g1, (unsigned)b, (unsigned)v) >> 9;
    if (bits > best || (bits == best && v < bv)) { best = bits; bv = v; }
  }
#pragma unroll
  for (int m = 1; m < 64; m <<= 1) {
    unsigned ob = __shfl_xor(best, m, 64);
    int      ov = __shfl_xor(bv,   m, 64);
    if (ob > best || (ob == best && ov < bv)) { best = ob; bv = ov; }
  }
  if (lane == 0) pre[job] = bv;
}

// ---------------- init: h=0, x=embedding[0] ----------------
__global__ void k_init_state(const float* __restrict__ emb,
                             float* __restrict__ x, float* __restrict__ h) {
  int b = blockIdx.x, tid = threadIdx.x;  // 256 threads
  x[b*E + tid] = emb[tid];
  h[b*H + tid] = 0.0f;
  h[b*H + 256 + tid] = 0.0f;
}

// ---------------- init: w_out -> bf16 in MFMA-fragment-major layout ----------
__global__ void k_cast_w(const float* __restrict__ w,
                         unsigned short* __restrict__ w_sw) {
  int g = blockIdx.x*256 + threadIdx.x;   // [0, V*H/8)
  int v  = g >> 6;
  int k0 = (g & 63) * 8;
  const float* src = w + (size_t)v*H + k0;
  union { unsigned short s[8]; u32x4 vv; } u;
#pragma unroll
  for (int e = 0; e < 8; e++) u.s[e] = f2bf(src[e]);
  *(u32x4*)&w_sw[frag_off(v, k0, H/32)] = u.vv;
}

// ---------------- GRU math helpers (accumulation semantics FROZEN) ----------
__device__ __forceinline__ float sigm_acc(float v) {
  return (float)(1.0 / (1.0 + exp(-(double)v)));
}
__device__ __forceinline__ float tanh_acc(float v) {
  return (float)tanh((double)v);
}

// ---------------- FUSED gate GEMMs + GRU (v2: dense-LDS + T14 prefetch) -----
// Block owns rows [row0,row0+64) x j-window [j0,j0+16) x all 3 gates, so the
// GRU for (row,j) is register-local (no gi/gh buffers, no cross-block deps,
// h double-buffered). Per-thread tile: 4 rows x 1 j x 3 gates -> per kk:
// 1 ds_read_b128 (4 A rows, 4-way lane broadcast) + 3 ds_read_b32 = 4 LDS
// instr per 12 fma (R5's fatal 5-per-6 ratio fixed). Staging is reg-prefetched
// (T14): next tile's 7 global loads issue before the 16-kk compute, written to
// the other LDS buffer after -> one barrier/tile, HBM/L2 latency hidden.
// NUMERICS FROZEN: each output's fmaf chain ascends k = 0..K-1 exactly as the
// original split kernels; bias adds and GRU ops identical -> bit-identical h.
// Grid (32, 8) x 256 threads = 256 blocks (1/CU).
__global__ __launch_bounds__(256) void k_gates_gru(
    const float* __restrict__ x, const float* __restrict__ hin,
    const float* __restrict__ w_ih, const float* __restrict__ w_hh,
    const float* __restrict__ b_ih, const float* __restrict__ b_hh,
    float* __restrict__ hout, unsigned short* __restrict__ h_sw) {
  __shared__ __align__(16) float As[2][16][68];   // 16k x 64 rows (+pad)
  __shared__ __align__(16) float Ws[2][16][52];   // 16k x 48 cols (+pad)
  const int tid = threadIdx.x;
  const int jw = tid & 15, rg = tid >> 4;    // jw 0..15, rg 0..15
  const int j0 = blockIdx.x * 16;            // j-window base
  const int row0 = blockIdx.y * 64;          // row-tile base

  float ai[4][3] = {};   // x-GEMM accumulators [row][gate]
  float ah[4][3] = {};   // h-GEMM accumulators

  float pa[4], pw[3];
  // prefetch tile 0 (x phase, k0 = 0)
#pragma unroll
  for (int l = 0; l < 4; l++) {
    int idx = tid + l*256;
    pa[l] = x[(size_t)(row0 + (idx >> 4))*E + (idx & 15)];
  }
#pragma unroll
  for (int l = 0; l < 3; l++) {
    int idx = tid + l*256;
    int c = idx >> 4;    // 0..47: gate = c>>4, jj = c&15
    pw[l] = w_ih[(size_t)((c >> 4)*512 + j0 + (c & 15))*E + (idx & 15)];
  }
  // write tile 0 -> buf 0
#pragma unroll
  for (int l = 0; l < 4; l++) {
    int idx = tid + l*256;
    As[0][idx & 15][idx >> 4] = pa[l];
  }
#pragma unroll
  for (int l = 0; l < 3; l++) {
    int idx = tid + l*256;
    Ws[0][idx & 15][idx >> 4] = pw[l];
  }
  __syncthreads();

  int p = 0;
#pragma unroll 1
  for (int tile = 0; tile < 48; tile++) {
    // ---- prefetch tile+1 into registers (issues loads; waits later) ----
    if (tile < 47) {
      const int nt = tile + 1;
      const float* A = (nt < 16) ? x    : hin;
      const float* W = (nt < 16) ? w_ih : w_hh;
      const int   K  = (nt < 16) ? E : H;
      const int   k0 = (nt < 16) ? nt*16 : (nt - 16)*16;
#pragma unroll
      for (int l = 0; l < 4; l++) {
        int idx = tid + l*256;
        pa[l] = A[(size_t)(row0 + (idx >> 4))*K + k0 + (idx & 15)];
      }
#pragma unroll
      for (int l = 0; l < 3; l++) {
        int idx = tid + l*256;
        int c = idx >> 4;
        pw[l] = W[(size_t)((c >> 4)*512 + j0 + (c & 15))*K + k0 + (idx & 15)];
      }
    }
    // ---- compute from buf[p] (k ascends: tile-major, kk-minor) ----
    if (tile < 16) {
#pragma unroll
      for (int kk = 0; kk < 16; kk++) {
        const float4 av = *(const float4*)&As[p][kk][rg*4];
        const float a[4] = {av.x, av.y, av.z, av.w};
        const float w0 = Ws[p][kk][jw];
        const float w1 = Ws[p][kk][16 + jw];
        const float w2 = Ws[p][kk][32 + jw];
#pragma unroll
        for (int i = 0; i < 4; i++) {
          ai[i][0] = fmaf(a[i], w0, ai[i][0]);
          ai[i][1] = fmaf(a[i], w1, ai[i][1]);
          ai[i][2] = fmaf(a[i], w2, ai[i][2]);
        }
      }
    } else {
#pragma unroll
      for (int kk = 0; kk < 16; kk++) {
        const float4 av = *(const float4*)&As[p][kk][rg*4];
        const float a[4] = {av.x, av.y, av.z, av.w};
        const float w0 = Ws[p][kk][jw];
        const float w1 = Ws[p][kk][16 + jw];
        const float w2 = Ws[p][kk][32 + jw];
#pragma unroll
        for (int i = 0; i < 4; i++) {
          ah[i][0] = fmaf(a[i], w0, ah[i][0]);
          ah[i][1] = fmaf(a[i], w1, ah[i][1]);
          ah[i][2] = fmaf(a[i], w2, ah[i][2]);
        }
      }
    }
    // ---- write prefetched regs -> buf[p^1] (nobody reads p^1 right now) ----
    if (tile < 47) {
#pragma unroll
      for (int l = 0; l < 4; l++) {
        int idx = tid + l*256;
        As[p ^ 1][idx & 15][idx >> 4] = pa[l];
      }
#pragma unroll
      for (int l = 0; l < 3; l++) {
        int idx = tid + l*256;
        Ws[p ^ 1][idx & 15][idx >> 4] = pw[l];
      }
      __syncthreads();
      p ^= 1;
    }
  }

  // ---- GRU in-register (math identical to the frozen k_gru_update) ----
  const int j = j0 + jw;
  const float bi_r = b_ih[j], bi_z = b_ih[512 + j], bi_n = b_ih[1024 + j];
  const float bh_r = b_hh[j], bh_z = b_hh[512 + j], bh_n = b_hh[1024 + j];
#pragma unroll
  for (int i = 0; i < 4; i++) {
    const int b = row0 + rg*4 + i;
    float gi_r = __fadd_rn(ai[i][0], bi_r);
    float gi_z = __fadd_rn(ai[i][1], bi_z);
    float gi_n = __fadd_rn(ai[i][2], bi_n);
    float gh_r = __fadd_rn(ah[i][0], bh_r);
    float gh_z = __fadd_rn(ah[i][1], bh_z);
    float gh_n = __fadd_rn(ah[i][2], bh_n);
    float r  = sigm_acc(__fadd_rn(gi_r, gh_r));
    float zz = sigm_acc(__fadd_rn(gi_z, gh_z));
    float nn = tanh_acc(__fadd_rn(gi_n, __fmul_rn(r, gh_n)));
    float hv = hin[(size_t)b*H + j];
    float t1 = __fmul_rn(__fsub_rn(1.0f, zz), nn);
    float t2 = __fmul_rn(zz, hv);
    float hn = __fadd_rn(t1, t2);
    hout[(size_t)b*H + j] = hn;
    h_sw[frag_off(b, j, H/32)] = f2bf(hn);
  }
}

// ---------------- bf16 MFMA logits GEMM: barrier-free direct-load -----------
// Tile 256(b) x 64(v), K=512. BOTH operands are fragment-major in global, so
// every wave direct-loads its A AND B fragments (16 B/lane contiguous) with a
// manual register double-buffer. No LDS, no __syncthreads in the K-loop.
// Grid (512, 3): y==0 pre-argmax slab for t+1; y in {1,2} the 1000 tiles,
// XCD-chunk swizzled so each XCD's L2 keeps a contiguous w_sw slice.
__global__ __launch_bounds__(256) void k_mfma_logits(
    const unsigned short* __restrict__ h_sw,
    const unsigned short* __restrict__ w_sw,
    const float* __restrict__ b_out,
    const unsigned* __restrict__ kq,
    const unsigned char* __restrict__ draws,
    int* __restrict__ pre,               // full [S*B] table
    const int* __restrict__ nd_slot_t,   // nd_slot + t*B
    float* __restrict__ pmax, float* __restrict__ psum,
    float* __restrict__ plog,
    float* __restrict__ nd_keys, float* __restrict__ nd_kmax, int t) {
  const int tid  = threadIdx.x;

  if (blockIdx.y == 0) {
    // ---- pre-argmax slab: drawn-row sample for step t+1 (bit-exact) ----
    __shared__ unsigned sb[4];
    __shared__ int      sv[4];
    const int tn = t + 1;
    if (tn >= S) return;
    const int b = blockIdx.x;            // 0..511
    if (!draws[tn*B + b]) { if (tid == 0) pre[tn*B + b] = -1; return; }
    const unsigned g0 = kq[2*tn], g1 = kq[2*tn+1];
    unsigned best = 0u; int bv = V;
    for (int v = tid; v < V; v += 256) {
      unsigned bits = rbits(g0, g1, (unsigned)b, (unsigned)v) >> 9;
      if (bits > best || (bits == best && v < bv)) { best = bits; bv = v; }
    }
#pragma unroll
    for (int m = 1; m < 64; m <<= 1) {
      unsigned ob = __shfl_xor(best, m, 64);
      int      ov = __shfl_xor(bv,   m, 64);
      if (ob > best || (ob == best && ov < bv)) { best = ob; bv = ov; }
    }
    const int wv = tid >> 6;
    if ((tid & 63) == 0) { sb[wv] = best; sv[wv] = bv; }
    __syncthreads();
    if (tid == 0) {
      for (int i = 1; i < 4; i++) {
        unsigned ob = sb[i]; int ov = sv[i];
        if (ob > best || (ob == best && ov < bv)) { best = ob; bv = ov; }
      }
      pre[tn*B + b] = bv;
    }
    return;
  }

  // ---- GEMM tiles: XCD-chunked bijective swizzle over 1024 slots ----
  const int L  = (blockIdx.y - 1) * 512 + blockIdx.x;  // == hw linear id - 512
  const int wg = (L & 7) * 128 + (L >> 3);             // 128 contiguous wg/XCD
  if (wg >= 2*NCH) return;                             // 24 idle slots
  const int vblk = wg >> 1;      // 0..499; 64 contiguous vblk per XCD = 4 MB
  const int bblk = wg & 1;       // both b-halves of a vblk on the same XCD
  const int* __restrict__ pre_t = pre + t*B;
  const int lane = tid & 63, w = tid >> 6;
  const int quad = lane >> 4, l15 = lane & 15;

  f32x4 acc[4][4] = {};

  const int mtBase = bblk*16 + w*4;   // h rowTile base for this wave
  const int ntBase = vblk*4;          // w rowTile base
  const unsigned short* hp = h_sw + (size_t)mtBase*16*512 + lane*8;
  const unsigned short* wp = w_sw + (size_t)ntBase*16*512 + lane*8;

  // prologue: load kt=0 fragments for A and B
  bf16x8 afc[4], bfc[4];
#pragma unroll
  for (int mt = 0; mt < 4; mt++)
    afc[mt] = __builtin_bit_cast(bf16x8, *(const u32x4*)(hp + (size_t)(mt*16)*512));
#pragma unroll
  for (int nt = 0; nt < 4; nt++)
    bfc[nt] = __builtin_bit_cast(bf16x8, *(const u32x4*)(wp + (size_t)(nt*16)*512));

#pragma unroll 1
  for (int kt = 0; kt < 15; kt++) {
    bf16x8 afn[4], bfn[4];
#pragma unroll
    for (int mt = 0; mt < 4; mt++)
      afn[mt] = __builtin_bit_cast(bf16x8,
          *(const u32x4*)(hp + (size_t)(mt*16 + kt + 1)*512));
#pragma unroll
    for (int nt = 0; nt < 4; nt++)
      bfn[nt] = __builtin_bit_cast(bf16x8,
          *(const u32x4*)(wp + (size_t)(nt*16 + kt + 1)*512));
#pragma unroll
    for (int mt = 0; mt < 4; mt++)
#pragma unroll
      for (int nt = 0; nt < 4; nt++)
        acc[mt][nt] = __builtin_amdgcn_mfma_f32_16x16x32_bf16(
            afc[mt], bfc[nt], acc[mt][nt], 0, 0, 0);
#pragma unroll
    for (int mt = 0; mt < 4; mt++) afc[mt] = afn[mt];
#pragma unroll
    for (int nt = 0; nt < 4; nt++) bfc[nt] = bfn[nt];
  }
  {  // kt = 15
#pragma unroll
    for (int mt = 0; mt < 4; mt++)
#pragma unroll
      for (int nt = 0; nt < 4; nt++)
        acc[mt][nt] = __builtin_amdgcn_mfma_f32_16x16x32_bf16(
            afc[mt], bfc[nt], acc[mt][nt], 0, 0, 0);
  }

  // epilogue: lane holds D[b = bW + mt*16 + quad*4 + r][v = vW + nt*16 + l15]
  const int bW = bblk*256 + w*64;
  const int vW = vblk*64;
  const unsigned g0 = kq[2*t], g1 = kq[2*t+1];
  float bias[4];
#pragma unroll
  for (int nt = 0; nt < 4; nt++) bias[nt] = b_out[vW + nt*16 + l15];

#pragma unroll
  for (int mt = 0; mt < 4; mt++) {
#pragma unroll
    for (int r = 0; r < 4; r++) {
      const int b = bW + mt*16 + quad*4 + r;
      float lg[4];
#pragma unroll
      for (int nt = 0; nt < 4; nt++) lg[nt] = acc[mt][nt][r] + bias[nt];
      float lmax = fmaxf(fmaxf(lg[0], lg[1]), fmaxf(lg[2], lg[3]));
#pragma unroll
      for (int m = 1; m < 16; m <<= 1) lmax = fmaxf(lmax, __shfl_xor(lmax, m, 64));
      float ls = 0.0f;
#pragma unroll
      for (int nt = 0; nt < 4; nt++) ls += __expf(lg[nt] - lmax);
#pragma unroll
      for (int m = 1; m < 16; m <<= 1) ls += __shfl_xor(ls, m, 64);
      if (l15 == 0) { pmax[b*NCH + vblk] = lmax; psum[b*NCH + vblk] = ls; }
      const int pr = pre_t[b];
      if (pr >= 0) {
        int rel = pr - vW;
        if (rel >= 0 && rel < 64 && (rel & 15) == l15) plog[b] = lg[rel >> 4];
      } else {
        const int slot = nd_slot_t[b];
        if (slot >= 0) {
          float key[4];
#pragma unroll
          for (int nt = 0; nt < 4; nt++)
            key[nt] = lg[nt] + gumbel_fast(
                rbits(g0, g1, (unsigned)b, (unsigned)(vW + nt*16 + l15)));
          float* dst = nd_keys + (size_t)slot*V + vW + l15;
#pragma unroll
          for (int nt = 0; nt < 4; nt++) dst[nt*16] = key[nt];
          float kmx = fmaxf(fmaxf(key[0], key[1]), fmaxf(key[2], key[3]));
#pragma unroll
          for (int m = 1; m < 16; m <<= 1) kmx = fmaxf(kmx, __shfl_xor(kmx, m, 64));
          if (l15 == 0) nd_kmax[slot*NCH + vblk] = kmx;
        }
      }
    }
  }
}

// ---------------- fused finish: lse + (nd candidate pick) + outputs ---------
__global__ __launch_bounds__(256) void k_finish(
    const float* __restrict__ pmax, const float* __restrict__ psum,
    const float* __restrict__ plog,
    const int* __restrict__ pre_t, const int* __restrict__ nd_slot_t,
    const float* __restrict__ nd_keys, const float* __restrict__ nd_kmax,
    const unsigned* __restrict__ kq,
    const float* __restrict__ h, const float* __restrict__ w_out,
    const float* __restrict__ b_out,
    const float* __restrict__ emb, float* __restrict__ x,
    float* __restrict__ out_samples, float* __restrict__ out_lps, int t) {
  const int b = blockIdx.x;
  const int tid = threadIdx.x;
  __shared__ float sA[256];
  __shared__ int   cand[160];
  __shared__ float cand_key[160], cand_lg[160];
  __shared__ int   ccnt;
  __shared__ int   s_samp;
  __shared__ float s_blog;

  // ---- softmax lse over 500 chunk partials ----
  float m = -INFINITY;
  for (int c = tid; c < NCH; c += 256) m = fmaxf(m, pmax[b*NCH + c]);
  sA[tid] = m; __syncthreads();
  for (int s = 128; s > 0; s >>= 1) {
    if (tid < s) sA[tid] = fmaxf(sA[tid], sA[tid+s]);
    __syncthreads();
  }
  const float M = sA[0];
  __syncthreads();
  float sum = 0.0f;
  for (int c = tid; c < NCH; c += 256)
    sum += psum[b*NCH + c] * expf(pmax[b*NCH + c] - M);
  sA[tid] = sum; __syncthreads();
  for (int s = 128; s > 0; s >>= 1) {
    if (tid < s) sA[tid] += sA[tid+s];
    __syncthreads();
  }
  const float SUM = sA[0];
  __syncthreads();

  // ---- pick the sample ----
  const int pr = pre_t[b];             // block-uniform
  if (pr >= 0) {
    if (tid == 0) { s_samp = pr; s_blog = plog[b]; }
  } else {
    const int slot = nd_slot_t[b];
    if (slot < 0) {                    // statistically impossible overflow guard
      if (tid == 0) { s_samp = 0; s_blog = plog[b]; }
    } else {
      const unsigned g0 = kq[2*t], g1 = kq[2*t+1];
      if (tid == 0) ccnt = 0;
      float km = -INFINITY;
      for (int c = tid; c < NCH; c += 256) km = fmaxf(km, nd_kmax[slot*NCH + c]);
      sA[tid] = km; __syncthreads();
      for (int s = 128; s > 0; s >>= 1) {
        if (tid < s) sA[tid] = fmaxf(sA[tid], sA[tid+s]);
        __syncthreads();
      }
      const float thr = sA[0] - 0.0859375f;  // >= 2*(bf16 err + fastlog err)
      __syncthreads();
      const float* keys = nd_keys + (size_t)slot*V;
      for (int c = tid; c < NCH; c += 256) {
        if (nd_kmax[slot*NCH + c] >= thr) {
          for (int j = 0; j < VBLK; j++) {
            float k = keys[c*VBLK + j];
            if (k >= thr) {
              int p = atomicAdd(&ccnt, 1);
              if (p < 160) cand[p] = c*VBLK + j;
            }
          }
        }
      }
      __syncthreads();
      const int nc = min(ccnt, 160);
      const int wid = tid >> 6, lane = tid & 63;
      for (int c = wid; c < nc; c += 4) {
        const int v = cand[c];
        const float* wr = w_out + (size_t)v*H;
        const float* hr = h + (size_t)b*H;
        float s = 0.0f;
#pragma unroll
        for (int i = 0; i < 8; i++) s = fmaf(hr[lane + 64*i], wr[lane + 64*i], s);
#pragma unroll
        for (int mm = 1; mm < 64; mm <<= 1) s += __shfl_xor(s, mm, 64);
        if (lane == 0) {
          float logit = __fadd_rn(s, b_out[v]);
          float key   = __fadd_rn(logit,
                          gumbel_exact(rbits(g0, g1, (unsigned)b, (unsigned)v)));
          cand_key[c] = key; cand_lg[c] = logit;
        }
      }
      __syncthreads();
      if (tid == 0) {
        float bk = -INFINITY; int bv = V; float bl = 0.0f;
        for (int c = 0; c < nc; c++) {
          float k = cand_key[c]; int v = cand[c];
          if (k > bk || (k == bk && v < bv)) { bk = k; bv = v; bl = cand_lg[c]; }
        }
        s_samp = bv; s_blog = bl;
      }
    }
  }
  __syncthreads();
  const int sampled = s_samp;
  if (tid == 0) {
    float lse = (float)log((double)SUM);
    float lp  = __fsub_rn(__fsub_rn(s_blog, M), lse);
    out_samples[b*S + t] = (float)sampled;
    out_lps[b*S + t]     = lp;
  }
  x[b*E + tid] = emb[sampled*E + tid];
}

} // namespace

extern "C" void kernel_launch(void* const* d_in, const int* in_sizes, int n_in,
                              void* d_out, int out_size, void* d_ws, size_t ws_size,
                              hipStream_t stream) {
  (void)in_sizes; (void)n_in; (void)out_size;
  const float* emb   = (const float*)d_in[0];
  const float* w_ih  = (const float*)d_in[1];
  const float* w_hh  = (const float*)d_in[2];
  const float* b_ih  = (const float*)d_in[3];
  const float* b_hh  = (const float*)d_in[4];
  const float* w_out = (const float*)d_in[5];
  const float* b_out = (const float*)d_in[6];
  float* out = (float*)d_out;

  char* wsb = (char*)d_ws;
  size_t off = 0;
  auto alloc = [&](size_t nbytes) {
    char* p = wsb + off;
    off += (nbytes + 255) & ~size_t(255);
    return p;
  };
  float* h0    = (float*)alloc((size_t)B*H*4);
  float* h1    = (float*)alloc((size_t)B*H*4);
  float* x     = (float*)alloc((size_t)B*E*4);
  unsigned short* h_sw = (unsigned short*)alloc((size_t)B*H*2);
  unsigned short* w_sw = (unsigned short*)alloc((size_t)V*H*2);
  float* pmax  = (float*)alloc((size_t)B*NCH*4);
  float* psum  = (float*)alloc((size_t)B*NCH*4);
  float* plog  = (float*)alloc((size_t)B*4);
  unsigned* kq = (unsigned*)alloc((size_t)S*2*4);
  unsigned* ke = (unsigned*)alloc((size_t)S*2*4);
  unsigned char* draws = (unsigned char*)alloc((size_t)S*B);
  int* pre     = (int*)alloc((size_t)S*B*4);
  int* nd_slot = (int*)alloc((size_t)S*B*4);
  float* nd_keys = (float*)alloc((size_t)NDMAX*V*4);
  float* nd_kmax = (float*)alloc((size_t)NDMAX*NCH*4);
  if (off > ws_size) {
    fprintf(stderr, "kernel_launch: workspace too small (need %zu, have %zu)\n",
            off, ws_size);
    return;
  }

  k_init_rng<<<1, S, 0, stream>>>(kq, ke);
  k_init_draws<<<S, B, 0, stream>>>(ke, draws);
  k_init_nd<<<S, 64, 0, stream>>>(draws, nd_slot);
  k_pre_argmax<<<B/4, 256, 0, stream>>>(kq, draws, pre);   // t=0 only
  k_init_state<<<B, 256, 0, stream>>>(emb, x, h0);
  k_cast_w<<<(V*H/8)/256, 256, 0, stream>>>(w_out, w_sw);

  for (int t = 0; t < S; t++) {
    float* hin  = (t & 1) ? h1 : h0;
    float* hout = (t & 1) ? h0 : h1;
    k_gates_gru<<<dim3(32, 8), 256, 0, stream>>>(x, hin, w_ih, w_hh,
                                                 b_ih, b_hh, hout, h_sw);
    k_mfma_logits<<<dim3(512, 3), 256, 0, stream>>>(
        h_sw, w_sw, b_out, kq, draws, pre, nd_slot + t*B,
        pmax, psum, plog, nd_keys, nd_kmax, t);
    k_finish<<<B, 256, 0, stream>>>(pmax, psum, plog, pre + t*B, nd_slot + t*B,
                                    nd_keys, nd_kmax, kq, hout, w_out, b_out,
                                    emb, x, out, out + (size_t)B*S, t);
  }
}

// Round 8
// 34696.771 us; speedup vs baseline: 1.7873x; 1.0585x over previous
//
#include <hip/hip_runtime.h>
#include <math.h>
#include <stdio.h>

#ifndef JAX_PARTITIONABLE
#define JAX_PARTITIONABLE 1
#endif

namespace {

constexpr int B  = 512;
constexpr int S  = 256;
constexpr int E  = 256;
constexpr int H  = 512;
constexpr int V  = 32000;
constexpr int G3 = 3 * H;      // 1536
constexpr int VBLK = 64;       // v-tile (also the softmax chunk width)
constexpr int NCH  = V / VBLK; // 500 chunks
constexpr int NDMAX = 96;      // max non-drawn rows per step (mean<=47)

typedef __bf16 bf16x8 __attribute__((ext_vector_type(8)));
typedef float  f32x4  __attribute__((ext_vector_type(4)));
typedef unsigned u32x4 __attribute__((ext_vector_type(4)));

// ---------------- Threefry-2x32, 20 rounds (bit-exact JAX) ----------------
__device__ __forceinline__ void tf2x32(unsigned k0, unsigned k1,
                                       unsigned x0, unsigned x1,
                                       unsigned& o0, unsigned& o1) {
  unsigned ks2 = k0 ^ k1 ^ 0x1BD11BDAu;
  x0 += k0; x1 += k1;
#define TFR(r) { x0 += x1; x1 = (x1 << (r)) | (x1 >> (32 - (r))); x1 ^= x0; }
  TFR(13) TFR(15) TFR(26) TFR(6)   x0 += k1;  x1 += ks2 + 1u;
  TFR(17) TFR(29) TFR(16) TFR(24)  x0 += ks2; x1 += k0 + 2u;
  TFR(13) TFR(15) TFR(26) TFR(6)   x0 += k0;  x1 += k1 + 3u;
  TFR(17) TFR(29) TFR(16) TFR(24)  x0 += k1;  x1 += ks2 + 4u;
  TFR(13) TFR(15) TFR(26) TFR(6)   x0 += ks2; x1 += k0 + 5u;
#undef TFR
  o0 = x0; o1 = x1;
}

__device__ __forceinline__ unsigned rbits(unsigned g0, unsigned g1,
                                          unsigned b, unsigned v) {
#if JAX_PARTITIONABLE
  unsigned y0, y1;
  tf2x32(g0, g1, 0u, b * (unsigned)V + v, y0, y1);
  return y0 ^ y1;
#else
  const unsigned N2 = (unsigned)(B/2) * (unsigned)V;
  unsigned ii = b * (unsigned)V + v;
  unsigned jj = (b < 256) ? ii : ii - N2;
  unsigned y0, y1;
  tf2x32(g0, g1, jj, N2 + jj, y0, y1);
  return (b < 256) ? y0 : y1;
#endif
}

__device__ __forceinline__ float u01_from_bits(unsigned bits) {
  return __uint_as_float(0x3f800000u | (bits >> 9)) - 1.0f;
}

__device__ __forceinline__ float gumbel_exact(unsigned bits) {
  float u = u01_from_bits(bits);
  if (u == 0.0f) u = 1.1754943508222875e-38f;
  float w = (float)(-log((double)u));
  return (float)(-log((double)w));
}

__device__ __forceinline__ float gumbel_fast(unsigned bits) {
  float u = u01_from_bits(bits);
  if (u == 0.0f) u = 1.1754943508222875e-38f;
  float w = -__logf(u);
  return -__logf(w);
}

__device__ __forceinline__ unsigned short f2bf(float f) {
  unsigned u = __float_as_uint(f);
  unsigned r = (u + 0x7fffu + ((u >> 16) & 1u)) >> 16;   // RNE, no NaN inputs
  return (unsigned short)r;
}

// fragment-major offset (in elements) for MFMA A/B operand layout:
// element (row, k) lives at [row>>4][k>>5][ (row&15) + 16*((k>>3)&3) ][ k&7 ]
__device__ __forceinline__ size_t frag_off(int row, int k, int kTiles) {
  return ((size_t)((row >> 4) * kTiles + (k >> 5)) * 64
          + (row & 15) + 16 * ((k >> 3) & 3)) * 8 + (k & 7);
}

// ---------------- init: per-step keys ----------------
__global__ void k_init_rng(unsigned* __restrict__ kq, unsigned* __restrict__ ke) {
  int t = threadIdx.x;  // 256 threads, 1 block
  unsigned h0, h1, e0, e1, g0, g1;
#if JAX_PARTITIONABLE
  tf2x32(0u, 42u, 0u, (unsigned)t, h0, h1);
  tf2x32(h0, h1, 0u, 0u, e0, e1);
  tf2x32(h0, h1, 0u, 1u, g0, g1);
#else
  unsigned a0, a1, b0, b1;
  if (t < 128) {
    tf2x32(0u, 42u, (unsigned)(2*t),   (unsigned)(256+2*t), a0, a1);
    tf2x32(0u, 42u, (unsigned)(2*t+1), (unsigned)(257+2*t), b0, b1);
    h0 = a0; h1 = b0;
  } else {
    int j = 2*t - 256;
    tf2x32(0u, 42u, (unsigned)j,     (unsigned)(256+j), a0, a1);
    tf2x32(0u, 42u, (unsigned)(j+1), (unsigned)(257+j), b0, b1);
    h0 = a1; h1 = b1;
  }
  unsigned p0, p1, q0, q1;
  tf2x32(h0, h1, 0u, 2u, p0, p1);
  tf2x32(h0, h1, 1u, 3u, q0, q1);
  e0 = p0; e1 = q0; g0 = p1; g1 = q1;
#endif
  ke[2*t] = e0; ke[2*t+1] = e1;
  kq[2*t] = g0; kq[2*t+1] = g1;
}

// ---------------- init: epsilon-greedy draw mask ----------------
__global__ void k_init_draws(const unsigned* __restrict__ ke,
                             unsigned char* __restrict__ draws) {
  int t = blockIdx.x;      // 0..255
  int b = threadIdx.x;     // 0..511
  unsigned k0 = ke[2*t], k1 = ke[2*t+1];
  unsigned bits, y0, y1;
#if JAX_PARTITIONABLE
  tf2x32(k0, k1, 0u, (unsigned)b, y0, y1);
  bits = y0 ^ y1;
#else
  if (b < 256) { tf2x32(k0, k1, (unsigned)b,       (unsigned)(256+b), y0, y1); bits = y0; }
  else         { tf2x32(k0, k1, (unsigned)(b-256), (unsigned)b,       y0, y1); bits = y1; }
#endif
  float u   = u01_from_bits(bits);
  float tf  = (float)t;
  float ex  = expf(__fmul_rn(-4.0f, tf) / 10000.0f);
  float eps = __fadd_rn(0.05f, __fmul_rn(0.95f, ex));
  draws[t*B + b] = (eps >= u) ? 1 : 0;
}

// ---------------- init: non-drawn slot assignment ----------------
__global__ void k_init_nd(const unsigned char* __restrict__ draws,
                          int* __restrict__ nd_slot) {
  int t = blockIdx.x;
  if (threadIdx.x != 0) return;
  int cnt = 0;
  for (int b = 0; b < B; b++) {
    if (!draws[t*B + b] && cnt < NDMAX) nd_slot[t*B + b] = cnt++;
    else nd_slot[t*B + b] = -1;
  }
}

// ---------------- init: drawn-row samples for t=0 only ----------------------
// (steady-state pre[t+1] is co-scheduled inside k_mfma_logits step t)
__global__ __launch_bounds__(256) void k_pre_argmax(
    const unsigned* __restrict__ kq, const unsigned char* __restrict__ draws,
    int* __restrict__ pre) {
  const int job  = blockIdx.x * 4 + (threadIdx.x >> 6);   // [0, B) at grid=B/4
  const int lane = threadIdx.x & 63;
  const int t = job >> 9, b = job & (B - 1);
  if (!draws[t*B + b]) { if (lane == 0) pre[job] = -1; return; }
  const unsigned g0 = kq[2*t], g1 = kq[2*t+1];
  unsigned best = 0u; int bv = V;
  for (int v = lane; v < V; v += 64) {
    unsigned bits = rbits(g0, g1, (unsigned)b, (unsigned)v) >> 9;
    if (bits > best || (bits == best && v < bv)) { best = bits; bv = v; }
  }
#pragma unroll
  for (int m = 1; m < 64; m <<= 1) {
    unsigned ob = __shfl_xor(best, m, 64);
    int      ov = __shfl_xor(bv,   m, 64);
    if (ob > best || (ob == best && ov < bv)) { best = ob; bv = ov; }
  }
  if (lane == 0) pre[job] = bv;
}

// ---------------- init: h=0, sample_prev=0 (token 0) ----------------
__global__ void k_init_state(float* __restrict__ h, int* __restrict__ samp) {
  int b = blockIdx.x, tid = threadIdx.x;  // 256 threads
  h[b*H + tid] = 0.0f;
  h[b*H + 256 + tid] = 0.0f;
  if (tid == 0) samp[b] = 0;
}

// ---------------- init: w_out -> bf16 in MFMA-fragment-major layout ----------
__global__ void k_cast_w(const float* __restrict__ w,
                         unsigned short* __restrict__ w_sw) {
  int g = blockIdx.x*256 + threadIdx.x;   // [0, V*H/8)
  int v  = g >> 6;
  int k0 = (g & 63) * 8;
  const float* src = w + (size_t)v*H + k0;
  union { unsigned short s[8]; u32x4 vv; } u;
#pragma unroll
  for (int e = 0; e < 8; e++) u.s[e] = f2bf(src[e]);
  *(u32x4*)&w_sw[frag_off(v, k0, H/32)] = u.vv;
}

// ---------------- GRU math helpers (accumulation semantics FROZEN) ----------
__device__ __forceinline__ float sigm_acc(float v) {
  return (float)(1.0 / (1.0 + exp(-(double)v)));
}
__device__ __forceinline__ float tanh_acc(float v) {
  return (float)tanh((double)v);
}

// ---------------- K_A: [h-GEMM(t) slab] || [finish(t-1) slab] ---------------
// The two slabs are mutually independent: h-GEMM reads h(t-1)/w_hh; finish
// reads logits(t-1) partials + h(t-1). Mixing them gives the gates blocks the
// co-resident occupancy R7 lacked while taking finish off the serial path.
// h-GEMM: block owns 64 rows x 16 j x 3 gates; per kk: 1 ds_read_b128 +
// 3 ds_read_b32 per 12 fma; T14 reg-prefetch double buffer; k ascends 0..H-1
// exactly as the frozen original; writes gh = acc + b_hh (same __fadd_rn).
// finish body: byte-identical to the verified k_finish (minus x write; adds
// sample int for K_B's gather).
__global__ __launch_bounds__(256) void k_gates_finish(
    const float* __restrict__ h, const float* __restrict__ w_hh,
    const float* __restrict__ b_hh, float* __restrict__ gh,
    const float* __restrict__ pmax, const float* __restrict__ psum,
    const float* __restrict__ plog,
    const int* __restrict__ pre, const int* __restrict__ nd_slot,
    const float* __restrict__ nd_keys, const float* __restrict__ nd_kmax,
    const unsigned* __restrict__ kq,
    const float* __restrict__ w_out, const float* __restrict__ b_out,
    float* __restrict__ out_samples, float* __restrict__ out_lps,
    int* __restrict__ samp, int t) {
  const int tid = threadIdx.x;
  union Sh {
    struct { float As[2][16][68]; float Ws[2][16][52]; } g;
    struct { float sA[256]; int cand[160]; float ck[160]; float cl[160];
             int ccnt; int samp; float blog; } f;
  };
  __shared__ Sh sh;

  if (blockIdx.x < 256) {
    // ================= h-GEMM slab for step t =================
    if (t >= S) return;                      // trailing finish-only launch
    const int jw = tid & 15, rg = tid >> 4;
    const int j0 = (blockIdx.x & 31) * 16;
    const int row0 = (blockIdx.x >> 5) * 64;
    float ah[4][3] = {};
    float pa[4], pw[3];
    // prefetch tile 0 (k0 = 0)
#pragma unroll
    for (int l = 0; l < 4; l++) {
      int idx = tid + l*256;
      pa[l] = h[(size_t)(row0 + (idx >> 4))*H + (idx & 15)];
    }
#pragma unroll
    for (int l = 0; l < 3; l++) {
      int idx = tid + l*256;
      int c = idx >> 4;
      pw[l] = w_hh[(size_t)((c >> 4)*512 + j0 + (c & 15))*H + (idx & 15)];
    }
#pragma unroll
    for (int l = 0; l < 4; l++) {
      int idx = tid + l*256;
      sh.g.As[0][idx & 15][idx >> 4] = pa[l];
    }
#pragma unroll
    for (int l = 0; l < 3; l++) {
      int idx = tid + l*256;
      sh.g.Ws[0][idx & 15][idx >> 4] = pw[l];
    }
    __syncthreads();
    int p = 0;
#pragma unroll 1
    for (int tile = 0; tile < 32; tile++) {
      if (tile < 31) {
        const int k0 = (tile + 1) * 16;
#pragma unroll
        for (int l = 0; l < 4; l++) {
          int idx = tid + l*256;
          pa[l] = h[(size_t)(row0 + (idx >> 4))*H + k0 + (idx & 15)];
        }
#pragma unroll
        for (int l = 0; l < 3; l++) {
          int idx = tid + l*256;
          int c = idx >> 4;
          pw[l] = w_hh[(size_t)((c >> 4)*512 + j0 + (c & 15))*H + k0 + (idx & 15)];
        }
      }
#pragma unroll
      for (int kk = 0; kk < 16; kk++) {
        const float4 av = *(const float4*)&sh.g.As[p][kk][rg*4];
        const float a[4] = {av.x, av.y, av.z, av.w};
        const float w0 = sh.g.Ws[p][kk][jw];
        const float w1 = sh.g.Ws[p][kk][16 + jw];
        const float w2 = sh.g.Ws[p][kk][32 + jw];
#pragma unroll
        for (int i = 0; i < 4; i++) {
          ah[i][0] = fmaf(a[i], w0, ah[i][0]);
          ah[i][1] = fmaf(a[i], w1, ah[i][1]);
          ah[i][2] = fmaf(a[i], w2, ah[i][2]);
        }
      }
      if (tile < 31) {
#pragma unroll
        for (int l = 0; l < 4; l++) {
          int idx = tid + l*256;
          sh.g.As[p ^ 1][idx & 15][idx >> 4] = pa[l];
        }
#pragma unroll
        for (int l = 0; l < 3; l++) {
          int idx = tid + l*256;
          sh.g.Ws[p ^ 1][idx & 15][idx >> 4] = pw[l];
        }
        __syncthreads();
        p ^= 1;
      }
    }
    const int j = j0 + jw;
    const float bh_r = b_hh[j], bh_z = b_hh[512 + j], bh_n = b_hh[1024 + j];
#pragma unroll
    for (int i = 0; i < 4; i++) {
      const int b = row0 + rg*4 + i;
      gh[(size_t)b*G3 +        j] = __fadd_rn(ah[i][0], bh_r);
      gh[(size_t)b*G3 +  512 + j] = __fadd_rn(ah[i][1], bh_z);
      gh[(size_t)b*G3 + 1024 + j] = __fadd_rn(ah[i][2], bh_n);
    }
    return;
  }

  // ================= finish slab for step t-1 =================
  const int tf = t - 1;
  if (tf < 0) return;
  const int b = blockIdx.x - 256;          // 0..511
  const int* pre_t     = pre + tf*B;
  const int* nd_slot_t = nd_slot + tf*B;

  float m = -INFINITY;
  for (int c = tid; c < NCH; c += 256) m = fmaxf(m, pmax[b*NCH + c]);
  sh.f.sA[tid] = m; __syncthreads();
  for (int s = 128; s > 0; s >>= 1) {
    if (tid < s) sh.f.sA[tid] = fmaxf(sh.f.sA[tid], sh.f.sA[tid+s]);
    __syncthreads();
  }
  const float M = sh.f.sA[0];
  __syncthreads();
  float sum = 0.0f;
  for (int c = tid; c < NCH; c += 256)
    sum += psum[b*NCH + c] * expf(pmax[b*NCH + c] - M);
  sh.f.sA[tid] = sum; __syncthreads();
  for (int s = 128; s > 0; s >>= 1) {
    if (tid < s) sh.f.sA[tid] += sh.f.sA[tid+s];
    __syncthreads();
  }
  const float SUM = sh.f.sA[0];
  __syncthreads();

  const int pr = pre_t[b];                 // block-uniform
  if (pr >= 0) {
    if (tid == 0) { sh.f.samp = pr; sh.f.blog = plog[b]; }
  } else {
    const int slot = nd_slot_t[b];
    if (slot < 0) {                        // statistically impossible guard
      if (tid == 0) { sh.f.samp = 0; sh.f.blog = plog[b]; }
    } else {
      const unsigned g0 = kq[2*tf], g1 = kq[2*tf+1];
      if (tid == 0) sh.f.ccnt = 0;
      float km = -INFINITY;
      for (int c = tid; c < NCH; c += 256) km = fmaxf(km, nd_kmax[slot*NCH + c]);
      sh.f.sA[tid] = km; __syncthreads();
      for (int s = 128; s > 0; s >>= 1) {
        if (tid < s) sh.f.sA[tid] = fmaxf(sh.f.sA[tid], sh.f.sA[tid+s]);
        __syncthreads();
      }
      const float thr = sh.f.sA[0] - 0.0859375f;  // >= 2*(bf16 + fastlog err)
      __syncthreads();
      const float* keys = nd_keys + (size_t)slot*V;
      for (int c = tid; c < NCH; c += 256) {
        if (nd_kmax[slot*NCH + c] >= thr) {
          for (int j = 0; j < VBLK; j++) {
            float k = keys[c*VBLK + j];
            if (k >= thr) {
              int p = atomicAdd(&sh.f.ccnt, 1);
              if (p < 160) sh.f.cand[p] = c*VBLK + j;
            }
          }
        }
      }
      __syncthreads();
      const int nc = min(sh.f.ccnt, 160);
      const int wid = tid >> 6, lane = tid & 63;
      for (int c = wid; c < nc; c += 4) {
        const int v = sh.f.cand[c];
        const float* wr = w_out + (size_t)v*H;
        const float* hr = h + (size_t)b*H;
        float s = 0.0f;
#pragma unroll
        for (int i = 0; i < 8; i++) s = fmaf(hr[lane + 64*i], wr[lane + 64*i], s);
#pragma unroll
        for (int mm = 1; mm < 64; mm <<= 1) s += __shfl_xor(s, mm, 64);
        if (lane == 0) {
          float logit = __fadd_rn(s, b_out[v]);
          float key   = __fadd_rn(logit,
                          gumbel_exact(rbits(g0, g1, (unsigned)b, (unsigned)v)));
          sh.f.ck[c] = key; sh.f.cl[c] = logit;
        }
      }
      __syncthreads();
      if (tid == 0) {
        float bk = -INFINITY; int bv = V; float bl = 0.0f;
        for (int c = 0; c < nc; c++) {
          float k = sh.f.ck[c]; int v = sh.f.cand[c];
          if (k > bk || (k == bk && v < bv)) { bk = k; bv = v; bl = sh.f.cl[c]; }
        }
        sh.f.samp = bv; sh.f.blog = bl;
      }
    }
  }
  __syncthreads();
  if (tid == 0) {
    const int sampled = sh.f.samp;
    float lse = (float)log((double)SUM);
    float lp  = __fsub_rn(__fsub_rn(sh.f.blog, M), lse);
    out_samples[b*S + tf] = (float)sampled;
    out_lps[b*S + tf]     = lp;
    samp[b] = sampled;
  }
}

// ---------------- K_B: x-GEMM (emb gather) + GRU -----------------------------
// Block owns 64 rows x 16 j x 3 gates over K=E (16 tiles). A rows are gathered
// emb[sample[row]] -- bit-identical values to the old x buffer. gh (with bias)
// read from global; GRU math identical to the frozen k_gru_update. Grid (32,8).
__global__ __launch_bounds__(256) void k_xgru(
    const float* __restrict__ emb, const int* __restrict__ samp,
    const float* __restrict__ w_ih, const float* __restrict__ b_ih,
    const float* __restrict__ gh, float* __restrict__ h,
    unsigned short* __restrict__ h_sw) {
  __shared__ __align__(16) float As[2][16][68];
  __shared__ __align__(16) float Ws[2][16][52];
  __shared__ int srow[64];
  const int tid = threadIdx.x;
  const int jw = tid & 15, rg = tid >> 4;
  const int j0 = blockIdx.x * 16;
  const int row0 = blockIdx.y * 64;
  if (tid < 64) srow[tid] = samp[row0 + tid];
  __syncthreads();

  float ai[4][3] = {};
  float pa[4], pw[3];
#pragma unroll
  for (int l = 0; l < 4; l++) {
    int idx = tid + l*256;
    pa[l] = emb[(size_t)srow[idx >> 4]*E + (idx & 15)];
  }
#pragma unroll
  for (int l = 0; l < 3; l++) {
    int idx = tid + l*256;
    int c = idx >> 4;
    pw[l] = w_ih[(size_t)((c >> 4)*512 + j0 + (c & 15))*E + (idx & 15)];
  }
#pragma unroll
  for (int l = 0; l < 4; l++) {
    int idx = tid + l*256;
    As[0][idx & 15][idx >> 4] = pa[l];
  }
#pragma unroll
  for (int l = 0; l < 3; l++) {
    int idx = tid + l*256;
    Ws[0][idx & 15][idx >> 4] = pw[l];
  }
  __syncthreads();
  int p = 0;
#pragma unroll 1
  for (int tile = 0; tile < 16; tile++) {
    if (tile < 15) {
      const int k0 = (tile + 1) * 16;
#pragma unroll
      for (int l = 0; l < 4; l++) {
        int idx = tid + l*256;
        pa[l] = emb[(size_t)srow[idx >> 4]*E + k0 + (idx & 15)];
      }
#pragma unroll
      for (int l = 0; l < 3; l++) {
        int idx = tid + l*256;
        int c = idx >> 4;
        pw[l] = w_ih[(size_t)((c >> 4)*512 + j0 + (c & 15))*E + k0 + (idx & 15)];
      }
    }
#pragma unroll
    for (int kk = 0; kk < 16; kk++) {
      const float4 av = *(const float4*)&As[p][kk][rg*4];
      const float a[4] = {av.x, av.y, av.z, av.w};
      const float w0 = Ws[p][kk][jw];
      const float w1 = Ws[p][kk][16 + jw];
      const float w2 = Ws[p][kk][32 + jw];
#pragma unroll
      for (int i = 0; i < 4; i++) {
        ai[i][0] = fmaf(a[i], w0, ai[i][0]);
        ai[i][1] = fmaf(a[i], w1, ai[i][1]);
        ai[i][2] = fmaf(a[i], w2, ai[i][2]);
      }
    }
    if (tile < 15) {
#pragma unroll
      for (int l = 0; l < 4; l++) {
        int idx = tid + l*256;
        As[p ^ 1][idx & 15][idx >> 4] = pa[l];
      }
#pragma unroll
      for (int l = 0; l < 3; l++) {
        int idx = tid + l*256;
        Ws[p ^ 1][idx & 15][idx >> 4] = pw[l];
      }
      __syncthreads();
      p ^= 1;
    }
  }

  // ---- GRU (math identical to the frozen k_gru_update) ----
  const int j = j0 + jw;
  const float bi_r = b_ih[j], bi_z = b_ih[512 + j], bi_n = b_ih[1024 + j];
#pragma unroll
  for (int i = 0; i < 4; i++) {
    const int b = row0 + rg*4 + i;
    float gi_r = __fadd_rn(ai[i][0], bi_r);
    float gi_z = __fadd_rn(ai[i][1], bi_z);
    float gi_n = __fadd_rn(ai[i][2], bi_n);
    float gh_r = gh[(size_t)b*G3 + j];
    float gh_z = gh[(size_t)b*G3 + 512 + j];
    float gh_n = gh[(size_t)b*G3 + 1024 + j];
    float r  = sigm_acc(__fadd_rn(gi_r, gh_r));
    float zz = sigm_acc(__fadd_rn(gi_z, gh_z));
    float nn = tanh_acc(__fadd_rn(gi_n, __fmul_rn(r, gh_n)));
    float hv = h[(size_t)b*H + j];
    float t1 = __fmul_rn(__fsub_rn(1.0f, zz), nn);
    float t2 = __fmul_rn(zz, hv);
    float hn = __fadd_rn(t1, t2);
    h[(size_t)b*H + j] = hn;
    h_sw[frag_off(b, j, H/32)] = f2bf(hn);
  }
}

// ---------------- K_C: bf16 MFMA logits GEMM (barrier-free direct-load) -----
// Unchanged from the verified R4 version. Grid (512,3): y==0 pre-argmax slab
// for t+1; y in {1,2} the 1000 tiles, XCD-chunk swizzled.
__global__ __launch_bounds__(256) void k_mfma_logits(
    const unsigned short* __restrict__ h_sw,
    const unsigned short* __restrict__ w_sw,
    const float* __restrict__ b_out,
    const unsigned* __restrict__ kq,
    const unsigned char* __restrict__ draws,
    int* __restrict__ pre,               // full [S*B] table
    const int* __restrict__ nd_slot_t,   // nd_slot + t*B
    float* __restrict__ pmax, float* __restrict__ psum,
    float* __restrict__ plog,
    float* __restrict__ nd_keys, float* __restrict__ nd_kmax, int t) {
  const int tid  = threadIdx.x;

  if (blockIdx.y == 0) {
    // ---- pre-argmax slab: drawn-row sample for step t+1 (bit-exact) ----
    __shared__ unsigned sb[4];
    __shared__ int      sv[4];
    const int tn = t + 1;
    if (tn >= S) return;
    const int b = blockIdx.x;            // 0..511
    if (!draws[tn*B + b]) { if (tid == 0) pre[tn*B + b] = -1; return; }
    const unsigned g0 = kq[2*tn], g1 = kq[2*tn+1];
    unsigned best = 0u; int bv = V;
    for (int v = tid; v < V; v += 256) {
      unsigned bits = rbits(g0, g1, (unsigned)b, (unsigned)v) >> 9;
      if (bits > best || (bits == best && v < bv)) { best = bits; bv = v; }
    }
#pragma unroll
    for (int m = 1; m < 64; m <<= 1) {
      unsigned ob = __shfl_xor(best, m, 64);
      int      ov = __shfl_xor(bv,   m, 64);
      if (ob > best || (ob == best && ov < bv)) { best = ob; bv = ov; }
    }
    const int wv = tid >> 6;
    if ((tid & 63) == 0) { sb[wv] = best; sv[wv] = bv; }
    __syncthreads();
    if (tid == 0) {
      for (int i = 1; i < 4; i++) {
        unsigned ob = sb[i]; int ov = sv[i];
        if (ob > best || (ob == best && ov < bv)) { best = ob; bv = ov; }
      }
      pre[tn*B + b] = bv;
    }
    return;
  }

  // ---- GEMM tiles: XCD-chunked bijective swizzle over 1024 slots ----
  const int L  = (blockIdx.y - 1) * 512 + blockIdx.x;  // == hw linear id - 512
  const int wg = (L & 7) * 128 + (L >> 3);             // 128 contiguous wg/XCD
  if (wg >= 2*NCH) return;                             // 24 idle slots
  const int vblk = wg >> 1;      // 0..499; 64 contiguous vblk per XCD = 4 MB
  const int bblk = wg & 1;       // both b-halves of a vblk on the same XCD
  const int* __restrict__ pre_t = pre + t*B;
  const int lane = tid & 63, w = tid >> 6;
  const int quad = lane >> 4, l15 = lane & 15;

  f32x4 acc[4][4] = {};

  const int mtBase = bblk*16 + w*4;   // h rowTile base for this wave
  const int ntBase = vblk*4;          // w rowTile base
  const unsigned short* hp = h_sw + (size_t)mtBase*16*512 + lane*8;
  const unsigned short* wp = w_sw + (size_t)ntBase*16*512 + lane*8;

  // prologue: load kt=0 fragments for A and B
  bf16x8 afc[4], bfc[4];
#pragma unroll
  for (int mt = 0; mt < 4; mt++)
    afc[mt] = __builtin_bit_cast(bf16x8, *(const u32x4*)(hp + (size_t)(mt*16)*512));
#pragma unroll
  for (int nt = 0; nt < 4; nt++)
    bfc[nt] = __builtin_bit_cast(bf16x8, *(const u32x4*)(wp + (size_t)(nt*16)*512));

#pragma unroll 1
  for (int kt = 0; kt < 15; kt++) {
    bf16x8 afn[4], bfn[4];
#pragma unroll
    for (int mt = 0; mt < 4; mt++)
      afn[mt] = __builtin_bit_cast(bf16x8,
          *(const u32x4*)(hp + (size_t)(mt*16 + kt + 1)*512));
#pragma unroll
    for (int nt = 0; nt < 4; nt++)
      bfn[nt] = __builtin_bit_cast(bf16x8,
          *(const u32x4*)(wp + (size_t)(nt*16 + kt + 1)*512));
#pragma unroll
    for (int mt = 0; mt < 4; mt++)
#pragma unroll
      for (int nt = 0; nt < 4; nt++)
        acc[mt][nt] = __builtin_amdgcn_mfma_f32_16x16x32_bf16(
            afc[mt], bfc[nt], acc[mt][nt], 0, 0, 0);
#pragma unroll
    for (int mt = 0; mt < 4; mt++) afc[mt] = afn[mt];
#pragma unroll
    for (int nt = 0; nt < 4; nt++) bfc[nt] = bfn[nt];
  }
  {  // kt = 15
#pragma unroll
    for (int mt = 0; mt < 4; mt++)
#pragma unroll
      for (int nt = 0; nt < 4; nt++)
        acc[mt][nt] = __builtin_amdgcn_mfma_f32_16x16x32_bf16(
            afc[mt], bfc[nt], acc[mt][nt], 0, 0, 0);
  }

  // epilogue: lane holds D[b = bW + mt*16 + quad*4 + r][v = vW + nt*16 + l15]
  const int bW = bblk*256 + w*64;
  const int vW = vblk*64;
  const unsigned g0 = kq[2*t], g1 = kq[2*t+1];
  float bias[4];
#pragma unroll
  for (int nt = 0; nt < 4; nt++) bias[nt] = b_out[vW + nt*16 + l15];

#pragma unroll
  for (int mt = 0; mt < 4; mt++) {
#pragma unroll
    for (int r = 0; r < 4; r++) {
      const int b = bW + mt*16 + quad*4 + r;
      float lg[4];
#pragma unroll
      for (int nt = 0; nt < 4; nt++) lg[nt] = acc[mt][nt][r] + bias[nt];
      float lmax = fmaxf(fmaxf(lg[0], lg[1]), fmaxf(lg[2], lg[3]));
#pragma unroll
      for (int m = 1; m < 16; m <<= 1) lmax = fmaxf(lmax, __shfl_xor(lmax, m, 64));
      float ls = 0.0f;
#pragma unroll
      for (int nt = 0; nt < 4; nt++) ls += __expf(lg[nt] - lmax);
#pragma unroll
      for (int m = 1; m < 16; m <<= 1) ls += __shfl_xor(ls, m, 64);
      if (l15 == 0) { pmax[b*NCH + vblk] = lmax; psum[b*NCH + vblk] = ls; }
      const int pr = pre_t[b];
      if (pr >= 0) {
        int rel = pr - vW;
        if (rel >= 0 && rel < 64 && (rel & 15) == l15) plog[b] = lg[rel >> 4];
      } else {
        const int slot = nd_slot_t[b];
        if (slot >= 0) {
          float key[4];
#pragma unroll
          for (int nt = 0; nt < 4; nt++)
            key[nt] = lg[nt] + gumbel_fast(
                rbits(g0, g1, (unsigned)b, (unsigned)(vW + nt*16 + l15)));
          float* dst = nd_keys + (size_t)slot*V + vW + l15;
#pragma unroll
          for (int nt = 0; nt < 4; nt++) dst[nt*16] = key[nt];
          float kmx = fmaxf(fmaxf(key[0], key[1]), fmaxf(key[2], key[3]));
#pragma unroll
          for (int m = 1; m < 16; m <<= 1) kmx = fmaxf(kmx, __shfl_xor(kmx, m, 64));
          if (l15 == 0) nd_kmax[slot*NCH + vblk] = kmx;
        }
      }
    }
  }
}

} // namespace

extern "C" void kernel_launch(void* const* d_in, const int* in_sizes, int n_in,
                              void* d_out, int out_size, void* d_ws, size_t ws_size,
                              hipStream_t stream) {
  (void)in_sizes; (void)n_in; (void)out_size;
  const float* emb   = (const float*)d_in[0];
  const float* w_ih  = (const float*)d_in[1];
  const float* w_hh  = (const float*)d_in[2];
  const float* b_ih  = (const float*)d_in[3];
  const float* b_hh  = (const float*)d_in[4];
  const float* w_out = (const float*)d_in[5];
  const float* b_out = (const float*)d_in[6];
  float* out = (float*)d_out;

  char* wsb = (char*)d_ws;
  size_t off = 0;
  auto alloc = [&](size_t nbytes) {
    char* p = wsb + off;
    off += (nbytes + 255) & ~size_t(255);
    return p;
  };
  float* h     = (float*)alloc((size_t)B*H*4);
  float* gh    = (float*)alloc((size_t)B*G3*4);
  unsigned short* h_sw = (unsigned short*)alloc((size_t)B*H*2);
  unsigned short* w_sw = (unsigned short*)alloc((size_t)V*H*2);
  float* pmax  = (float*)alloc((size_t)B*NCH*4);
  float* psum  = (float*)alloc((size_t)B*NCH*4);
  float* plog  = (float*)alloc((size_t)B*4);
  unsigned* kq = (unsigned*)alloc((size_t)S*2*4);
  unsigned* ke = (unsigned*)alloc((size_t)S*2*4);
  unsigned char* draws = (unsigned char*)alloc((size_t)S*B);
  int* pre     = (int*)alloc((size_t)S*B*4);
  int* nd_slot = (int*)alloc((size_t)S*B*4);
  float* nd_keys = (float*)alloc((size_t)NDMAX*V*4);
  float* nd_kmax = (float*)alloc((size_t)NDMAX*NCH*4);
  int* samp    = (int*)alloc((size_t)B*4);
  if (off > ws_size) {
    fprintf(stderr, "kernel_launch: workspace too small (need %zu, have %zu)\n",
            off, ws_size);
    return;
  }

  k_init_rng<<<1, S, 0, stream>>>(kq, ke);
  k_init_draws<<<S, B, 0, stream>>>(ke, draws);
  k_init_nd<<<S, 64, 0, stream>>>(draws, nd_slot);
  k_pre_argmax<<<B/4, 256, 0, stream>>>(kq, draws, pre);   // t=0 only
  k_init_state<<<B, 256, 0, stream>>>(h, samp);
  k_cast_w<<<(V*H/8)/256, 256, 0, stream>>>(w_out, w_sw);

  for (int t = 0; t < S; t++) {
    k_gates_finish<<<768, 256, 0, stream>>>(
        h, w_hh, b_hh, gh, pmax, psum, plog, pre, nd_slot,
        nd_keys, nd_kmax, kq, w_out, b_out,
        out, out + (size_t)B*S, samp, t);
    k_xgru<<<dim3(32, 8), 256, 0, stream>>>(emb, samp, w_ih, b_ih,
                                            gh, h, h_sw);
    k_mfma_logits<<<dim3(512, 3), 256, 0, stream>>>(
        h_sw, w_sw, b_out, kq, draws, pre, nd_slot + t*B,
        pmax, psum, plog, nd_keys, nd_kmax, t);
  }
  // trailing finish for t = S-1 (gates slab self-disables at t >= S)
  k_gates_finish<<<768, 256, 0, stream>>>(
      h, w_hh, b_hh, gh, pmax, psum, plog, pre, nd_slot,
      nd_keys, nd_kmax, kq, w_out, b_out,
      out, out + (size_t)B*S, samp, S);
}

// Round 9
// 33867.517 us; speedup vs baseline: 1.8311x; 1.0245x over previous
//
#include <hip/hip_runtime.h>
#include <math.h>
#include <stdio.h>

#ifndef JAX_PARTITIONABLE
#define JAX_PARTITIONABLE 1
#endif

namespace {

constexpr int B  = 512;
constexpr int S  = 256;
constexpr int E  = 256;
constexpr int H  = 512;
constexpr int V  = 32000;
constexpr int G3 = 3 * H;      // 1536
constexpr int VBLK = 64;       // v-tile (also the softmax chunk width)
constexpr int NCH  = V / VBLK; // 500 chunks
constexpr int NDMAX = 96;      // max non-drawn rows per step (mean<=47)

typedef __bf16 bf16x8 __attribute__((ext_vector_type(8)));
typedef float  f32x4  __attribute__((ext_vector_type(4)));
typedef unsigned u32x4 __attribute__((ext_vector_type(4)));

// ---------------- Threefry-2x32, 20 rounds (bit-exact JAX) ----------------
__device__ __forceinline__ void tf2x32(unsigned k0, unsigned k1,
                                       unsigned x0, unsigned x1,
                                       unsigned& o0, unsigned& o1) {
  unsigned ks2 = k0 ^ k1 ^ 0x1BD11BDAu;
  x0 += k0; x1 += k1;
#define TFR(r) { x0 += x1; x1 = (x1 << (r)) | (x1 >> (32 - (r))); x1 ^= x0; }
  TFR(13) TFR(15) TFR(26) TFR(6)   x0 += k1;  x1 += ks2 + 1u;
  TFR(17) TFR(29) TFR(16) TFR(24)  x0 += ks2; x1 += k0 + 2u;
  TFR(13) TFR(15) TFR(26) TFR(6)   x0 += k0;  x1 += k1 + 3u;
  TFR(17) TFR(29) TFR(16) TFR(24)  x0 += k1;  x1 += ks2 + 4u;
  TFR(13) TFR(15) TFR(26) TFR(6)   x0 += ks2; x1 += k0 + 5u;
#undef TFR
  o0 = x0; o1 = x1;
}

__device__ __forceinline__ unsigned rbits(unsigned g0, unsigned g1,
                                          unsigned b, unsigned v) {
#if JAX_PARTITIONABLE
  unsigned y0, y1;
  tf2x32(g0, g1, 0u, b * (unsigned)V + v, y0, y1);
  return y0 ^ y1;
#else
  const unsigned N2 = (unsigned)(B/2) * (unsigned)V;
  unsigned ii = b * (unsigned)V + v;
  unsigned jj = (b < 256) ? ii : ii - N2;
  unsigned y0, y1;
  tf2x32(g0, g1, jj, N2 + jj, y0, y1);
  return (b < 256) ? y0 : y1;
#endif
}

__device__ __forceinline__ float u01_from_bits(unsigned bits) {
  return __uint_as_float(0x3f800000u | (bits >> 9)) - 1.0f;
}

__device__ __forceinline__ float gumbel_exact(unsigned bits) {
  float u = u01_from_bits(bits);
  if (u == 0.0f) u = 1.1754943508222875e-38f;
  float w = (float)(-log((double)u));
  return (float)(-log((double)w));
}

__device__ __forceinline__ float gumbel_fast(unsigned bits) {
  float u = u01_from_bits(bits);
  if (u == 0.0f) u = 1.1754943508222875e-38f;
  float w = -__logf(u);
  return -__logf(w);
}

__device__ __forceinline__ unsigned short f2bf(float f) {
  unsigned u = __float_as_uint(f);
  unsigned r = (u + 0x7fffu + ((u >> 16) & 1u)) >> 16;   // RNE, no NaN inputs
  return (unsigned short)r;
}

// fragment-major offset (in elements) for MFMA A/B operand layout:
// element (row, k) lives at [row>>4][k>>5][ (row&15) + 16*((k>>3)&3) ][ k&7 ]
__device__ __forceinline__ size_t frag_off(int row, int k, int kTiles) {
  return ((size_t)((row >> 4) * kTiles + (k >> 5)) * 64
          + (row & 15) + 16 * ((k >> 3) & 3)) * 8 + (k & 7);
}

// ---------------- init: per-step keys ----------------
__global__ void k_init_rng(unsigned* __restrict__ kq, unsigned* __restrict__ ke) {
  int t = threadIdx.x;  // 256 threads, 1 block
  unsigned h0, h1, e0, e1, g0, g1;
#if JAX_PARTITIONABLE
  tf2x32(0u, 42u, 0u, (unsigned)t, h0, h1);
  tf2x32(h0, h1, 0u, 0u, e0, e1);
  tf2x32(h0, h1, 0u, 1u, g0, g1);
#else
  unsigned a0, a1, b0, b1;
  if (t < 128) {
    tf2x32(0u, 42u, (unsigned)(2*t),   (unsigned)(256+2*t), a0, a1);
    tf2x32(0u, 42u, (unsigned)(2*t+1), (unsigned)(257+2*t), b0, b1);
    h0 = a0; h1 = b0;
  } else {
    int j = 2*t - 256;
    tf2x32(0u, 42u, (unsigned)j,     (unsigned)(256+j), a0, a1);
    tf2x32(0u, 42u, (unsigned)(j+1), (unsigned)(257+j), b0, b1);
    h0 = a1; h1 = b1;
  }
  unsigned p0, p1, q0, q1;
  tf2x32(h0, h1, 0u, 2u, p0, p1);
  tf2x32(h0, h1, 1u, 3u, q0, q1);
  e0 = p0; e1 = q0; g0 = p1; g1 = q1;
#endif
  ke[2*t] = e0; ke[2*t+1] = e1;
  kq[2*t] = g0; kq[2*t+1] = g1;
}

// ---------------- init: epsilon-greedy draw mask ----------------
__global__ void k_init_draws(const unsigned* __restrict__ ke,
                             unsigned char* __restrict__ draws) {
  int t = blockIdx.x;      // 0..255
  int b = threadIdx.x;     // 0..511
  unsigned k0 = ke[2*t], k1 = ke[2*t+1];
  unsigned bits, y0, y1;
#if JAX_PARTITIONABLE
  tf2x32(k0, k1, 0u, (unsigned)b, y0, y1);
  bits = y0 ^ y1;
#else
  if (b < 256) { tf2x32(k0, k1, (unsigned)b,       (unsigned)(256+b), y0, y1); bits = y0; }
  else         { tf2x32(k0, k1, (unsigned)(b-256), (unsigned)b,       y0, y1); bits = y1; }
#endif
  float u   = u01_from_bits(bits);
  float tf  = (float)t;
  float ex  = expf(__fmul_rn(-4.0f, tf) / 10000.0f);
  float eps = __fadd_rn(0.05f, __fmul_rn(0.95f, ex));
  draws[t*B + b] = (eps >= u) ? 1 : 0;
}

// ---------------- init: non-drawn slot assignment ----------------
__global__ void k_init_nd(const unsigned char* __restrict__ draws,
                          int* __restrict__ nd_slot) {
  int t = blockIdx.x;
  if (threadIdx.x != 0) return;
  int cnt = 0;
  for (int b = 0; b < B; b++) {
    if (!draws[t*B + b] && cnt < NDMAX) nd_slot[t*B + b] = cnt++;
    else nd_slot[t*B + b] = -1;
  }
}

// ---------------- init: drawn-row samples for t=0 only ----------------------
// (steady-state pre[t+1] is a slab inside k_gates_finish at step t)
__global__ __launch_bounds__(256) void k_pre_argmax(
    const unsigned* __restrict__ kq, const unsigned char* __restrict__ draws,
    int* __restrict__ pre) {
  const int job  = blockIdx.x * 4 + (threadIdx.x >> 6);   // [0, B) at grid=B/4
  const int lane = threadIdx.x & 63;
  const int t = job >> 9, b = job & (B - 1);
  if (!draws[t*B + b]) { if (lane == 0) pre[job] = -1; return; }
  const unsigned g0 = kq[2*t], g1 = kq[2*t+1];
  unsigned best = 0u; int bv = V;
  for (int v = lane; v < V; v += 64) {
    unsigned bits = rbits(g0, g1, (unsigned)b, (unsigned)v) >> 9;
    if (bits > best || (bits == best && v < bv)) { best = bits; bv = v; }
  }
#pragma unroll
  for (int m = 1; m < 64; m <<= 1) {
    unsigned ob = __shfl_xor(best, m, 64);
    int      ov = __shfl_xor(bv,   m, 64);
    if (ob > best || (ob == best && ov < bv)) { best = ob; bv = ov; }
  }
  if (lane == 0) pre[job] = bv;
}

// ---------------- init: h=0, sample_prev=0 (token 0) ----------------
__global__ void k_init_state(float* __restrict__ h, int* __restrict__ samp) {
  int b = blockIdx.x, tid = threadIdx.x;  // 256 threads
  h[b*H + tid] = 0.0f;
  h[b*H + 256 + tid] = 0.0f;
  if (tid == 0) samp[b] = 0;
}

// ---------------- init: w_out -> bf16 in MFMA-fragment-major layout ----------
__global__ void k_cast_w(const float* __restrict__ w,
                         unsigned short* __restrict__ w_sw) {
  int g = blockIdx.x*256 + threadIdx.x;   // [0, V*H/8)
  int v  = g >> 6;
  int k0 = (g & 63) * 8;
  const float* src = w + (size_t)v*H + k0;
  union { unsigned short s[8]; u32x4 vv; } u;
#pragma unroll
  for (int e = 0; e < 8; e++) u.s[e] = f2bf(src[e]);
  *(u32x4*)&w_sw[frag_off(v, k0, H/32)] = u.vv;
}

// ---------------- init: EG[v] = emb[v] @ w_ih^T + b_ih  (one-time) ----------
// Same 64x64/512-thread tiling as the verified R4 k_gates; each output's fmaf
// chain ascends k = 0..E-1 and bias is added with the same __fadd_rn ->
// EG[samp[b]][c] is BIT-IDENTICAL to the old per-step gi[b][c].
__global__ __launch_bounds__(512) void k_emb_gates(
    const float* __restrict__ emb, const float* __restrict__ w_ih,
    const float* __restrict__ b_ih, float* __restrict__ EG) {
  __shared__ __align__(16) float As[16][68];
  __shared__ __align__(16) float Ws[16][68];
  const int tid = threadIdx.x;             // 0..511
  const int tx = tid & 15, ty = tid >> 4;  // ty 0..31
  const int row0 = blockIdx.y * 64, col0 = blockIdx.x * 64;
  float acc[2][4] = {};
  for (int k0 = 0; k0 < E; k0 += 16) {
#pragma unroll
    for (int l = 0; l < 2; l++) {
      int idx = tid + l*512;
      int r = idx >> 4, kk = idx & 15;
      As[kk][r] = emb[(size_t)(row0 + r)*E + k0 + kk];
      Ws[kk][r] = w_ih[(size_t)(col0 + r)*E + k0 + kk];
    }
    __syncthreads();
#pragma unroll
    for (int kk = 0; kk < 16; kk++) {
      const float2 av = *(const float2*)&As[kk][ty*2];
      const float4 wv = *(const float4*)&Ws[kk][tx*4];
      const float a[2] = {av.x, av.y};
      const float w[4] = {wv.x, wv.y, wv.z, wv.w};
#pragma unroll
      for (int i = 0; i < 2; i++)
#pragma unroll
        for (int j = 0; j < 4; j++) acc[i][j] = fmaf(a[i], w[j], acc[i][j]);
    }
    __syncthreads();
  }
#pragma unroll
  for (int i = 0; i < 2; i++) {
    int r = row0 + ty*2 + i;
    int c = col0 + tx*4;
    float4 o;
    o.x = __fadd_rn(acc[i][0], b_ih[c + 0]);
    o.y = __fadd_rn(acc[i][1], b_ih[c + 1]);
    o.z = __fadd_rn(acc[i][2], b_ih[c + 2]);
    o.w = __fadd_rn(acc[i][3], b_ih[c + 3]);
    *(float4*)&EG[(size_t)r*G3 + c] = o;
  }
}

// ---------------- GRU math helpers (accumulation semantics FROZEN) ----------
__device__ __forceinline__ float sigm_acc(float v) {
  return (float)(1.0 / (1.0 + exp(-(double)v)));
}
__device__ __forceinline__ float tanh_acc(float v) {
  return (float)tanh((double)v);
}

// ---------------- K_A: [h-GEMM(t)] || [finish(t-1)] || [pre(t+1)] -----------
// Three mutually independent slabs:
//  bx <  256 : h-GEMM(t)   -- gh(t) from h(t-1), w_hh   (R8-verified tiling)
//  bx <  768 : finish(t-1) -- samp/outputs from logits(t-1) partials + h(t-1)
//  bx < 1280 : pre(t+1)    -- drawn-row argmax from kq/draws only
// The light finish/pre blocks fill the latency slack of the 256 h-GEMM blocks.
__global__ __launch_bounds__(256) void k_gates_finish(
    const float* __restrict__ h, const float* __restrict__ w_hh,
    const float* __restrict__ b_hh, float* __restrict__ gh,
    const float* __restrict__ pmax, const float* __restrict__ psum,
    const float* __restrict__ plog,
    int* __restrict__ pre, const int* __restrict__ nd_slot,
    const float* __restrict__ nd_keys, const float* __restrict__ nd_kmax,
    const unsigned* __restrict__ kq, const unsigned char* __restrict__ draws,
    const float* __restrict__ w_out, const float* __restrict__ b_out,
    float* __restrict__ out_samples, float* __restrict__ out_lps,
    int* __restrict__ samp, int t) {
  const int tid = threadIdx.x;
  union Sh {
    struct { float As[2][16][68]; float Ws[2][16][52]; } g;
    struct { float sA[256]; int cand[160]; float ck[160]; float cl[160];
             int ccnt; int samp; float blog; } f;
    struct { unsigned sb[4]; int sv[4]; } p;
  };
  __shared__ Sh sh;

  if (blockIdx.x < 256) {
    // ================= h-GEMM slab for step t =================
    if (t >= S) return;                      // trailing finish-only launch
    const int jw = tid & 15, rg = tid >> 4;
    const int j0 = (blockIdx.x & 31) * 16;
    const int row0 = (blockIdx.x >> 5) * 64;
    float ah[4][3] = {};
    float pa[4], pw[3];
    // prefetch tile 0 (k0 = 0)
#pragma unroll
    for (int l = 0; l < 4; l++) {
      int idx = tid + l*256;
      pa[l] = h[(size_t)(row0 + (idx >> 4))*H + (idx & 15)];
    }
#pragma unroll
    for (int l = 0; l < 3; l++) {
      int idx = tid + l*256;
      int c = idx >> 4;
      pw[l] = w_hh[(size_t)((c >> 4)*512 + j0 + (c & 15))*H + (idx & 15)];
    }
#pragma unroll
    for (int l = 0; l < 4; l++) {
      int idx = tid + l*256;
      sh.g.As[0][idx & 15][idx >> 4] = pa[l];
    }
#pragma unroll
    for (int l = 0; l < 3; l++) {
      int idx = tid + l*256;
      sh.g.Ws[0][idx & 15][idx >> 4] = pw[l];
    }
    __syncthreads();
    int p = 0;
#pragma unroll 1
    for (int tile = 0; tile < 32; tile++) {
      if (tile < 31) {
        const int k0 = (tile + 1) * 16;
#pragma unroll
        for (int l = 0; l < 4; l++) {
          int idx = tid + l*256;
          pa[l] = h[(size_t)(row0 + (idx >> 4))*H + k0 + (idx & 15)];
        }
#pragma unroll
        for (int l = 0; l < 3; l++) {
          int idx = tid + l*256;
          int c = idx >> 4;
          pw[l] = w_hh[(size_t)((c >> 4)*512 + j0 + (c & 15))*H + k0 + (idx & 15)];
        }
      }
#pragma unroll
      for (int kk = 0; kk < 16; kk++) {
        const float4 av = *(const float4*)&sh.g.As[p][kk][rg*4];
        const float a[4] = {av.x, av.y, av.z, av.w};
        const float w0 = sh.g.Ws[p][kk][jw];
        const float w1 = sh.g.Ws[p][kk][16 + jw];
        const float w2 = sh.g.Ws[p][kk][32 + jw];
#pragma unroll
        for (int i = 0; i < 4; i++) {
          ah[i][0] = fmaf(a[i], w0, ah[i][0]);
          ah[i][1] = fmaf(a[i], w1, ah[i][1]);
          ah[i][2] = fmaf(a[i], w2, ah[i][2]);
        }
      }
      if (tile < 31) {
#pragma unroll
        for (int l = 0; l < 4; l++) {
          int idx = tid + l*256;
          sh.g.As[p ^ 1][idx & 15][idx >> 4] = pa[l];
        }
#pragma unroll
        for (int l = 0; l < 3; l++) {
          int idx = tid + l*256;
          sh.g.Ws[p ^ 1][idx & 15][idx >> 4] = pw[l];
        }
        __syncthreads();
        p ^= 1;
      }
    }
    const int j = j0 + jw;
    const float bh_r = b_hh[j], bh_z = b_hh[512 + j], bh_n = b_hh[1024 + j];
#pragma unroll
    for (int i = 0; i < 4; i++) {
      const int b = row0 + rg*4 + i;
      gh[(size_t)b*G3 +        j] = __fadd_rn(ah[i][0], bh_r);
      gh[(size_t)b*G3 +  512 + j] = __fadd_rn(ah[i][1], bh_z);
      gh[(size_t)b*G3 + 1024 + j] = __fadd_rn(ah[i][2], bh_n);
    }
    return;
  }

  if (blockIdx.x >= 768) {
    // ================= pre-argmax slab for step t+1 (bit-exact) ============
    const int tn = t + 1;
    if (tn >= S) return;
    const int b = blockIdx.x - 768;          // 0..511
    if (!draws[tn*B + b]) { if (tid == 0) pre[tn*B + b] = -1; return; }
    const unsigned g0 = kq[2*tn], g1 = kq[2*tn+1];
    unsigned best = 0u; int bv = V;
    for (int v = tid; v < V; v += 256) {
      unsigned bits = rbits(g0, g1, (unsigned)b, (unsigned)v) >> 9;
      if (bits > best || (bits == best && v < bv)) { best = bits; bv = v; }
    }
#pragma unroll
    for (int m = 1; m < 64; m <<= 1) {
      unsigned ob = __shfl_xor(best, m, 64);
      int      ov = __shfl_xor(bv,   m, 64);
      if (ob > best || (ob == best && ov < bv)) { best = ob; bv = ov; }
    }
    const int wv = tid >> 6;
    if ((tid & 63) == 0) { sh.p.sb[wv] = best; sh.p.sv[wv] = bv; }
    __syncthreads();
    if (tid == 0) {
      for (int i = 1; i < 4; i++) {
        unsigned ob = sh.p.sb[i]; int ov = sh.p.sv[i];
        if (ob > best || (ob == best && ov < bv)) { best = ob; bv = ov; }
      }
      pre[tn*B + b] = bv;
    }
    return;
  }

  // ================= finish slab for step t-1 =================
  const int tf = t - 1;
  if (tf < 0) return;
  const int b = blockIdx.x - 256;          // 0..511
  const int* pre_t     = pre + tf*B;
  const int* nd_slot_t = nd_slot + tf*B;

  float m = -INFINITY;
  for (int c = tid; c < NCH; c += 256) m = fmaxf(m, pmax[b*NCH + c]);
  sh.f.sA[tid] = m; __syncthreads();
  for (int s = 128; s > 0; s >>= 1) {
    if (tid < s) sh.f.sA[tid] = fmaxf(sh.f.sA[tid], sh.f.sA[tid+s]);
    __syncthreads();
  }
  const float M = sh.f.sA[0];
  __syncthreads();
  float sum = 0.0f;
  for (int c = tid; c < NCH; c += 256)
    sum += psum[b*NCH + c] * expf(pmax[b*NCH + c] - M);
  sh.f.sA[tid] = sum; __syncthreads();
  for (int s = 128; s > 0; s >>= 1) {
    if (tid < s) sh.f.sA[tid] += sh.f.sA[tid+s];
    __syncthreads();
  }
  const float SUM = sh.f.sA[0];
  __syncthreads();

  const int pr = pre_t[b];                 // block-uniform
  if (pr >= 0) {
    if (tid == 0) { sh.f.samp = pr; sh.f.blog = plog[b]; }
  } else {
    const int slot = nd_slot_t[b];
    if (slot < 0) {                        // statistically impossible guard
      if (tid == 0) { sh.f.samp = 0; sh.f.blog = plog[b]; }
    } else {
      const unsigned g0 = kq[2*tf], g1 = kq[2*tf+1];
      if (tid == 0) sh.f.ccnt = 0;
      float km = -INFINITY;
      for (int c = tid; c < NCH; c += 256) km = fmaxf(km, nd_kmax[slot*NCH + c]);
      sh.f.sA[tid] = km; __syncthreads();
      for (int s = 128; s > 0; s >>= 1) {
        if (tid < s) sh.f.sA[tid] = fmaxf(sh.f.sA[tid], sh.f.sA[tid+s]);
        __syncthreads();
      }
      const float thr = sh.f.sA[0] - 0.0859375f;  // >= 2*(bf16 + fastlog err)
      __syncthreads();
      const float* keys = nd_keys + (size_t)slot*V;
      for (int c = tid; c < NCH; c += 256) {
        if (nd_kmax[slot*NCH + c] >= thr) {
          for (int j = 0; j < VBLK; j++) {
            float k = keys[c*VBLK + j];
            if (k >= thr) {
              int p = atomicAdd(&sh.f.ccnt, 1);
              if (p < 160) sh.f.cand[p] = c*VBLK + j;
            }
          }
        }
      }
      __syncthreads();
      const int nc = min(sh.f.ccnt, 160);
      const int wid = tid >> 6, lane = tid & 63;
      for (int c = wid; c < nc; c += 4) {
        const int v = sh.f.cand[c];
        const float* wr = w_out + (size_t)v*H;
        const float* hr = h + (size_t)b*H;
        float s = 0.0f;
#pragma unroll
        for (int i = 0; i < 8; i++) s = fmaf(hr[lane + 64*i], wr[lane + 64*i], s);
#pragma unroll
        for (int mm = 1; mm < 64; mm <<= 1) s += __shfl_xor(s, mm, 64);
        if (lane == 0) {
          float logit = __fadd_rn(s, b_out[v]);
          float key   = __fadd_rn(logit,
                          gumbel_exact(rbits(g0, g1, (unsigned)b, (unsigned)v)));
          sh.f.ck[c] = key; sh.f.cl[c] = logit;
        }
      }
      __syncthreads();
      if (tid == 0) {
        float bk = -INFINITY; int bv = V; float bl = 0.0f;
        for (int c = 0; c < nc; c++) {
          float k = sh.f.ck[c]; int v = sh.f.cand[c];
          if (k > bk || (k == bk && v < bv)) { bk = k; bv = v; bl = sh.f.cl[c]; }
        }
        sh.f.samp = bv; sh.f.blog = bl;
      }
    }
  }
  __syncthreads();
  if (tid == 0) {
    const int sampled = sh.f.samp;
    float lse = (float)log((double)SUM);
    float lp  = __fsub_rn(__fsub_rn(sh.f.blog, M), lse);
    out_samples[b*S + tf] = (float)sampled;
    out_lps[b*S + tf]     = lp;
    samp[b] = sampled;
  }
}

// ---------------- K_B (fast): gather gi from EG + GRU ------------------------
// gi(t)[b] = EG[samp[b]] -- bit-identical to the old x-GEMM output (EG built
// with the same fmaf chains + bias). GRU math identical to frozen k_gru_update.
__global__ void k_gru(const float* __restrict__ EG, const int* __restrict__ samp,
                      const float* __restrict__ gh, float* __restrict__ h,
                      unsigned short* __restrict__ h_sw) {
  int g = blockIdx.x*256 + threadIdx.x;   // [0, B*H/8)
  int b  = g >> 6;
  int j0 = (g & 63) * 8;
  const float* gib = EG + (size_t)samp[b]*G3;
  const float* ghb = gh + (size_t)b*G3;
  float hn[8];
  union { unsigned short s[8]; u32x4 vv; } u;
#pragma unroll
  for (int e = 0; e < 8; e++) {
    int j = j0 + e;
    float r  = sigm_acc(__fadd_rn(gib[j],     ghb[j]));
    float zz = sigm_acc(__fadd_rn(gib[H+j],   ghb[H+j]));
    float nn = tanh_acc(__fadd_rn(gib[2*H+j], __fmul_rn(r, ghb[2*H+j])));
    float hv = h[(size_t)b*H + j];
    float t1 = __fmul_rn(__fsub_rn(1.0f, zz), nn);
    float t2 = __fmul_rn(zz, hv);
    hn[e] = __fadd_rn(t1, t2);
    u.s[e] = f2bf(hn[e]);
  }
#pragma unroll
  for (int e = 0; e < 8; e++) h[(size_t)b*H + j0 + e] = hn[e];
  *(u32x4*)&h_sw[frag_off(b, j0, H/32)] = u.vv;
}

// ---------------- K_B (fallback): x-GEMM (emb gather) + GRU ------------------
// Used only if the workspace can't hold EG. Verified in R8.
__global__ __launch_bounds__(256) void k_xgru(
    const float* __restrict__ emb, const int* __restrict__ samp,
    const float* __restrict__ w_ih, const float* __restrict__ b_ih,
    const float* __restrict__ gh, float* __restrict__ h,
    unsigned short* __restrict__ h_sw) {
  __shared__ __align__(16) float As[2][16][68];
  __shared__ __align__(16) float Ws[2][16][52];
  __shared__ int srow[64];
  const int tid = threadIdx.x;
  const int jw = tid & 15, rg = tid >> 4;
  const int j0 = blockIdx.x * 16;
  const int row0 = blockIdx.y * 64;
  if (tid < 64) srow[tid] = samp[row0 + tid];
  __syncthreads();

  float ai[4][3] = {};
  float pa[4], pw[3];
#pragma unroll
  for (int l = 0; l < 4; l++) {
    int idx = tid + l*256;
    pa[l] = emb[(size_t)srow[idx >> 4]*E + (idx & 15)];
  }
#pragma unroll
  for (int l = 0; l < 3; l++) {
    int idx = tid + l*256;
    int c = idx >> 4;
    pw[l] = w_ih[(size_t)((c >> 4)*512 + j0 + (c & 15))*E + (idx & 15)];
  }
#pragma unroll
  for (int l = 0; l < 4; l++) {
    int idx = tid + l*256;
    As[0][idx & 15][idx >> 4] = pa[l];
  }
#pragma unroll
  for (int l = 0; l < 3; l++) {
    int idx = tid + l*256;
    Ws[0][idx & 15][idx >> 4] = pw[l];
  }
  __syncthreads();
  int p = 0;
#pragma unroll 1
  for (int tile = 0; tile < 16; tile++) {
    if (tile < 15) {
      const int k0 = (tile + 1) * 16;
#pragma unroll
      for (int l = 0; l < 4; l++) {
        int idx = tid + l*256;
        pa[l] = emb[(size_t)srow[idx >> 4]*E + k0 + (idx & 15)];
      }
#pragma unroll
      for (int l = 0; l < 3; l++) {
        int idx = tid + l*256;
        int c = idx >> 4;
        pw[l] = w_ih[(size_t)((c >> 4)*512 + j0 + (c & 15))*E + k0 + (idx & 15)];
      }
    }
#pragma unroll
    for (int kk = 0; kk < 16; kk++) {
      const float4 av = *(const float4*)&As[p][kk][rg*4];
      const float a[4] = {av.x, av.y, av.z, av.w};
      const float w0 = Ws[p][kk][jw];
      const float w1 = Ws[p][kk][16 + jw];
      const float w2 = Ws[p][kk][32 + jw];
#pragma unroll
      for (int i = 0; i < 4; i++) {
        ai[i][0] = fmaf(a[i], w0, ai[i][0]);
        ai[i][1] = fmaf(a[i], w1, ai[i][1]);
        ai[i][2] = fmaf(a[i], w2, ai[i][2]);
      }
    }
    if (tile < 15) {
#pragma unroll
      for (int l = 0; l < 4; l++) {
        int idx = tid + l*256;
        As[p ^ 1][idx & 15][idx >> 4] = pa[l];
      }
#pragma unroll
      for (int l = 0; l < 3; l++) {
        int idx = tid + l*256;
        Ws[p ^ 1][idx & 15][idx >> 4] = pw[l];
      }
      __syncthreads();
      p ^= 1;
    }
  }

  const int j = j0 + jw;
  const float bi_r = b_ih[j], bi_z = b_ih[512 + j], bi_n = b_ih[1024 + j];
#pragma unroll
  for (int i = 0; i < 4; i++) {
    const int b = row0 + rg*4 + i;
    float gi_r = __fadd_rn(ai[i][0], bi_r);
    float gi_z = __fadd_rn(ai[i][1], bi_z);
    float gi_n = __fadd_rn(ai[i][2], bi_n);
    float gh_r = gh[(size_t)b*G3 + j];
    float gh_z = gh[(size_t)b*G3 + 512 + j];
    float gh_n = gh[(size_t)b*G3 + 1024 + j];
    float r  = sigm_acc(__fadd_rn(gi_r, gh_r));
    float zz = sigm_acc(__fadd_rn(gi_z, gh_z));
    float nn = tanh_acc(__fadd_rn(gi_n, __fmul_rn(r, gh_n)));
    float hv = h[(size_t)b*H + j];
    float t1 = __fmul_rn(__fsub_rn(1.0f, zz), nn);
    float t2 = __fmul_rn(zz, hv);
    float hn = __fadd_rn(t1, t2);
    h[(size_t)b*H + j] = hn;
    h_sw[frag_off(b, j, H/32)] = f2bf(hn);
  }
}

// ---------------- K_C: bf16 MFMA logits GEMM (barrier-free direct-load) -----
// R4-verified tile path; pre slab removed (now lives in K_A). Grid (512,2):
// 1024 slots, XCD-chunk swizzled; 24 idle.
__global__ __launch_bounds__(256) void k_mfma_logits(
    const unsigned short* __restrict__ h_sw,
    const unsigned short* __restrict__ w_sw,
    const float* __restrict__ b_out,
    const unsigned* __restrict__ kq,
    const int* __restrict__ pre_t,       // pre + t*B
    const int* __restrict__ nd_slot_t,   // nd_slot + t*B
    float* __restrict__ pmax, float* __restrict__ psum,
    float* __restrict__ plog,
    float* __restrict__ nd_keys, float* __restrict__ nd_kmax, int t) {
  const int tid  = threadIdx.x;

  const int L  = blockIdx.y * 512 + blockIdx.x;        // 0..1023
  const int wg = (L & 7) * 128 + (L >> 3);             // 128 contiguous wg/XCD
  if (wg >= 2*NCH) return;                             // 24 idle slots
  const int vblk = wg >> 1;      // 0..499; 64 contiguous vblk per XCD = 4 MB
  const int bblk = wg & 1;       // both b-halves of a vblk on the same XCD
  const int lane = tid & 63, w = tid >> 6;
  const int quad = lane >> 4, l15 = lane & 15;

  f32x4 acc[4][4] = {};

  const int mtBase = bblk*16 + w*4;   // h rowTile base for this wave
  const int ntBase = vblk*4;          // w rowTile base
  const unsigned short* hp = h_sw + (size_t)mtBase*16*512 + lane*8;
  const unsigned short* wp = w_sw + (size_t)ntBase*16*512 + lane*8;

  // prologue: load kt=0 fragments for A and B
  bf16x8 afc[4], bfc[4];
#pragma unroll
  for (int mt = 0; mt < 4; mt++)
    afc[mt] = __builtin_bit_cast(bf16x8, *(const u32x4*)(hp + (size_t)(mt*16)*512));
#pragma unroll
  for (int nt = 0; nt < 4; nt++)
    bfc[nt] = __builtin_bit_cast(bf16x8, *(const u32x4*)(wp + (size_t)(nt*16)*512));

#pragma unroll 1
  for (int kt = 0; kt < 15; kt++) {
    bf16x8 afn[4], bfn[4];
#pragma unroll
    for (int mt = 0; mt < 4; mt++)
      afn[mt] = __builtin_bit_cast(bf16x8,
          *(const u32x4*)(hp + (size_t)(mt*16 + kt + 1)*512));
#pragma unroll
    for (int nt = 0; nt < 4; nt++)
      bfn[nt] = __builtin_bit_cast(bf16x8,
          *(const u32x4*)(wp + (size_t)(nt*16 + kt + 1)*512));
#pragma unroll
    for (int mt = 0; mt < 4; mt++)
#pragma unroll
      for (int nt = 0; nt < 4; nt++)
        acc[mt][nt] = __builtin_amdgcn_mfma_f32_16x16x32_bf16(
            afc[mt], bfc[nt], acc[mt][nt], 0, 0, 0);
#pragma unroll
    for (int mt = 0; mt < 4; mt++) afc[mt] = afn[mt];
#pragma unroll
    for (int nt = 0; nt < 4; nt++) bfc[nt] = bfn[nt];
  }
  {  // kt = 15
#pragma unroll
    for (int mt = 0; mt < 4; mt++)
#pragma unroll
      for (int nt = 0; nt < 4; nt++)
        acc[mt][nt] = __builtin_amdgcn_mfma_f32_16x16x32_bf16(
            afc[mt], bfc[nt], acc[mt][nt], 0, 0, 0);
  }

  // epilogue: lane holds D[b = bW + mt*16 + quad*4 + r][v = vW + nt*16 + l15]
  const int bW = bblk*256 + w*64;
  const int vW = vblk*64;
  const unsigned g0 = kq[2*t], g1 = kq[2*t+1];
  float bias[4];
#pragma unroll
  for (int nt = 0; nt < 4; nt++) bias[nt] = b_out[vW + nt*16 + l15];

#pragma unroll
  for (int mt = 0; mt < 4; mt++) {
#pragma unroll
    for (int r = 0; r < 4; r++) {
      const int b = bW + mt*16 + quad*4 + r;
      float lg[4];
#pragma unroll
      for (int nt = 0; nt < 4; nt++) lg[nt] = acc[mt][nt][r] + bias[nt];
      float lmax = fmaxf(fmaxf(lg[0], lg[1]), fmaxf(lg[2], lg[3]));
#pragma unroll
      for (int m = 1; m < 16; m <<= 1) lmax = fmaxf(lmax, __shfl_xor(lmax, m, 64));
      float ls = 0.0f;
#pragma unroll
      for (int nt = 0; nt < 4; nt++) ls += __expf(lg[nt] - lmax);
#pragma unroll
      for (int m = 1; m < 16; m <<= 1) ls += __shfl_xor(ls, m, 64);
      if (l15 == 0) { pmax[b*NCH + vblk] = lmax; psum[b*NCH + vblk] = ls; }
      const int pr = pre_t[b];
      if (pr >= 0) {
        int rel = pr - vW;
        if (rel >= 0 && rel < 64 && (rel & 15) == l15) plog[b] = lg[rel >> 4];
      } else {
        const int slot = nd_slot_t[b];
        if (slot >= 0) {
          float key[4];
#pragma unroll
          for (int nt = 0; nt < 4; nt++)
            key[nt] = lg[nt] + gumbel_fast(
                rbits(g0, g1, (unsigned)b, (unsigned)(vW + nt*16 + l15)));
          float* dst = nd_keys + (size_t)slot*V + vW + l15;
#pragma unroll
          for (int nt = 0; nt < 4; nt++) dst[nt*16] = key[nt];
          float kmx = fmaxf(fmaxf(key[0], key[1]), fmaxf(key[2], key[3]));
#pragma unroll
          for (int m = 1; m < 16; m <<= 1) kmx = fmaxf(kmx, __shfl_xor(kmx, m, 64));
          if (l15 == 0) nd_kmax[slot*NCH + vblk] = kmx;
        }
      }
    }
  }
}

} // namespace

extern "C" void kernel_launch(void* const* d_in, const int* in_sizes, int n_in,
                              void* d_out, int out_size, void* d_ws, size_t ws_size,
                              hipStream_t stream) {
  (void)in_sizes; (void)n_in; (void)out_size;
  const float* emb   = (const float*)d_in[0];
  const float* w_ih  = (const float*)d_in[1];
  const float* w_hh  = (const float*)d_in[2];
  const float* b_ih  = (const float*)d_in[3];
  const float* b_hh  = (const float*)d_in[4];
  const float* w_out = (const float*)d_in[5];
  const float* b_out = (const float*)d_in[6];
  float* out = (float*)d_out;

  char* wsb = (char*)d_ws;
  size_t off = 0;
  auto alloc = [&](size_t nbytes) {
    char* p = wsb + off;
    off += (nbytes + 255) & ~size_t(255);
    return p;
  };
  float* h     = (float*)alloc((size_t)B*H*4);
  float* gh    = (float*)alloc((size_t)B*G3*4);
  unsigned short* h_sw = (unsigned short*)alloc((size_t)B*H*2);
  unsigned short* w_sw = (unsigned short*)alloc((size_t)V*H*2);
  float* pmax  = (float*)alloc((size_t)B*NCH*4);
  float* psum  = (float*)alloc((size_t)B*NCH*4);
  float* plog  = (float*)alloc((size_t)B*4);
  unsigned* kq = (unsigned*)alloc((size_t)S*2*4);
  unsigned* ke = (unsigned*)alloc((size_t)S*2*4);
  unsigned char* draws = (unsigned char*)alloc((size_t)S*B);
  int* pre     = (int*)alloc((size_t)S*B*4);
  int* nd_slot = (int*)alloc((size_t)S*B*4);
  float* nd_keys = (float*)alloc((size_t)NDMAX*V*4);
  float* nd_kmax = (float*)alloc((size_t)NDMAX*NCH*4);
  int* samp    = (int*)alloc((size_t)B*4);
  if (off > ws_size) {
    fprintf(stderr, "kernel_launch: workspace too small (need %zu, have %zu)\n",
            off, ws_size);
    return;
  }
  // EG (196.6 MB) allocated last; fall back to the per-step x-GEMM if it
  // doesn't fit.
  const size_t eg_bytes = ((size_t)V*G3*4 + 255) & ~size_t(255);
  const bool use_eg = (off + eg_bytes <= ws_size);
  float* EG = use_eg ? (float*)alloc(eg_bytes) : nullptr;

  k_init_rng<<<1, S, 0, stream>>>(kq, ke);
  k_init_draws<<<S, B, 0, stream>>>(ke, draws);
  k_init_nd<<<S, 64, 0, stream>>>(draws, nd_slot);
  k_pre_argmax<<<B/4, 256, 0, stream>>>(kq, draws, pre);   // t=0 only
  k_init_state<<<B, 256, 0, stream>>>(h, samp);
  k_cast_w<<<(V*H/8)/256, 256, 0, stream>>>(w_out, w_sw);
  if (use_eg)
    k_emb_gates<<<dim3(G3/64, V/64), 512, 0, stream>>>(emb, w_ih, b_ih, EG);

  for (int t = 0; t < S; t++) {
    k_gates_finish<<<1280, 256, 0, stream>>>(
        h, w_hh, b_hh, gh, pmax, psum, plog, pre, nd_slot,
        nd_keys, nd_kmax, kq, draws, w_out, b_out,
        out, out + (size_t)B*S, samp, t);
    if (use_eg)
      k_gru<<<(B*H/8)/256, 256, 0, stream>>>(EG, samp, gh, h, h_sw);
    else
      k_xgru<<<dim3(32, 8), 256, 0, stream>>>(emb, samp, w_ih, b_ih,
                                              gh, h, h_sw);
    k_mfma_logits<<<dim3(512, 2), 256, 0, stream>>>(
        h_sw, w_sw, b_out, kq, pre + t*B, nd_slot + t*B,
        pmax, psum, plog, nd_keys, nd_kmax, t);
  }
  // trailing finish for t = S-1 (h-GEMM and pre slabs self-disable at t >= S)
  k_gates_finish<<<1280, 256, 0, stream>>>(
      h, w_hh, b_hh, gh, pmax, psum, plog, pre, nd_slot,
      nd_keys, nd_kmax, kq, draws, w_out, b_out,
      out, out + (size_t)B*S, samp, S);
}

// Round 10
// 32954.858 us; speedup vs baseline: 1.8818x; 1.0277x over previous
//
#include <hip/hip_runtime.h>
#include <math.h>
#include <stdio.h>

#ifndef JAX_PARTITIONABLE
#define JAX_PARTITIONABLE 1
#endif

namespace {

constexpr int B  = 512;
constexpr int S  = 256;
constexpr int E  = 256;
constexpr int H  = 512;
constexpr int V  = 32000;
constexpr int G3 = 3 * H;      // 1536
constexpr int VBLK = 64;       // v-tile (also the softmax chunk width)
constexpr int NCH  = V / VBLK; // 500 chunks
constexpr int NDMAX = 96;      // max non-drawn rows per step (mean<=47)

typedef __bf16 bf16x8 __attribute__((ext_vector_type(8)));
typedef float  f32x4  __attribute__((ext_vector_type(4)));
typedef unsigned u32x4 __attribute__((ext_vector_type(4)));

// ---------------- Threefry-2x32, 20 rounds (bit-exact JAX) ----------------
__device__ __forceinline__ void tf2x32(unsigned k0, unsigned k1,
                                       unsigned x0, unsigned x1,
                                       unsigned& o0, unsigned& o1) {
  unsigned ks2 = k0 ^ k1 ^ 0x1BD11BDAu;
  x0 += k0; x1 += k1;
#define TFR(r) { x0 += x1; x1 = (x1 << (r)) | (x1 >> (32 - (r))); x1 ^= x0; }
  TFR(13) TFR(15) TFR(26) TFR(6)   x0 += k1;  x1 += ks2 + 1u;
  TFR(17) TFR(29) TFR(16) TFR(24)  x0 += ks2; x1 += k0 + 2u;
  TFR(13) TFR(15) TFR(26) TFR(6)   x0 += k0;  x1 += k1 + 3u;
  TFR(17) TFR(29) TFR(16) TFR(24)  x0 += k1;  x1 += ks2 + 4u;
  TFR(13) TFR(15) TFR(26) TFR(6)   x0 += ks2; x1 += k0 + 5u;
#undef TFR
  o0 = x0; o1 = x1;
}

__device__ __forceinline__ unsigned rbits(unsigned g0, unsigned g1,
                                          unsigned b, unsigned v) {
#if JAX_PARTITIONABLE
  unsigned y0, y1;
  tf2x32(g0, g1, 0u, b * (unsigned)V + v, y0, y1);
  return y0 ^ y1;
#else
  const unsigned N2 = (unsigned)(B/2) * (unsigned)V;
  unsigned ii = b * (unsigned)V + v;
  unsigned jj = (b < 256) ? ii : ii - N2;
  unsigned y0, y1;
  tf2x32(g0, g1, jj, N2 + jj, y0, y1);
  return (b < 256) ? y0 : y1;
#endif
}

__device__ __forceinline__ float u01_from_bits(unsigned bits) {
  return __uint_as_float(0x3f800000u | (bits >> 9)) - 1.0f;
}

__device__ __forceinline__ float gumbel_exact(unsigned bits) {
  float u = u01_from_bits(bits);
  if (u == 0.0f) u = 1.1754943508222875e-38f;
  float w = (float)(-log((double)u));
  return (float)(-log((double)w));
}

__device__ __forceinline__ float gumbel_fast(unsigned bits) {
  float u = u01_from_bits(bits);
  if (u == 0.0f) u = 1.1754943508222875e-38f;
  float w = -__logf(u);
  return -__logf(w);
}

__device__ __forceinline__ unsigned short f2bf(float f) {
  unsigned u = __float_as_uint(f);
  unsigned r = (u + 0x7fffu + ((u >> 16) & 1u)) >> 16;   // RNE, no NaN inputs
  return (unsigned short)r;
}

// fragment-major offset (in elements) for MFMA A/B operand layout:
// element (row, k) lives at [row>>4][k>>5][ (row&15) + 16*((k>>3)&3) ][ k&7 ]
__device__ __forceinline__ size_t frag_off(int row, int k, int kTiles) {
  return ((size_t)((row >> 4) * kTiles + (k >> 5)) * 64
          + (row & 15) + 16 * ((k >> 3) & 3)) * 8 + (k & 7);
}

// ---------------- init: per-step keys ----------------
__global__ void k_init_rng(unsigned* __restrict__ kq, unsigned* __restrict__ ke) {
  int t = threadIdx.x;  // 256 threads, 1 block
  unsigned h0, h1, e0, e1, g0, g1;
#if JAX_PARTITIONABLE
  tf2x32(0u, 42u, 0u, (unsigned)t, h0, h1);
  tf2x32(h0, h1, 0u, 0u, e0, e1);
  tf2x32(h0, h1, 0u, 1u, g0, g1);
#else
  unsigned a0, a1, b0, b1;
  if (t < 128) {
    tf2x32(0u, 42u, (unsigned)(2*t),   (unsigned)(256+2*t), a0, a1);
    tf2x32(0u, 42u, (unsigned)(2*t+1), (unsigned)(257+2*t), b0, b1);
    h0 = a0; h1 = b0;
  } else {
    int j = 2*t - 256;
    tf2x32(0u, 42u, (unsigned)j,     (unsigned)(256+j), a0, a1);
    tf2x32(0u, 42u, (unsigned)(j+1), (unsigned)(257+j), b0, b1);
    h0 = a1; h1 = b1;
  }
  unsigned p0, p1, q0, q1;
  tf2x32(h0, h1, 0u, 2u, p0, p1);
  tf2x32(h0, h1, 1u, 3u, q0, q1);
  e0 = p0; e1 = q0; g0 = p1; g1 = q1;
#endif
  ke[2*t] = e0; ke[2*t+1] = e1;
  kq[2*t] = g0; kq[2*t+1] = g1;
}

// ---------------- init: epsilon-greedy draw mask ----------------
__global__ void k_init_draws(const unsigned* __restrict__ ke,
                             unsigned char* __restrict__ draws) {
  int t = blockIdx.x;      // 0..255
  int b = threadIdx.x;     // 0..511
  unsigned k0 = ke[2*t], k1 = ke[2*t+1];
  unsigned bits, y0, y1;
#if JAX_PARTITIONABLE
  tf2x32(k0, k1, 0u, (unsigned)b, y0, y1);
  bits = y0 ^ y1;
#else
  if (b < 256) { tf2x32(k0, k1, (unsigned)b,       (unsigned)(256+b), y0, y1); bits = y0; }
  else         { tf2x32(k0, k1, (unsigned)(b-256), (unsigned)b,       y0, y1); bits = y1; }
#endif
  float u   = u01_from_bits(bits);
  float tf  = (float)t;
  float ex  = expf(__fmul_rn(-4.0f, tf) / 10000.0f);
  float eps = __fadd_rn(0.05f, __fmul_rn(0.95f, ex));
  draws[t*B + b] = (eps >= u) ? 1 : 0;
}

// ---------------- init: non-drawn slot assignment ----------------
__global__ void k_init_nd(const unsigned char* __restrict__ draws,
                          int* __restrict__ nd_slot) {
  int t = blockIdx.x;
  if (threadIdx.x != 0) return;
  int cnt = 0;
  for (int b = 0; b < B; b++) {
    if (!draws[t*B + b] && cnt < NDMAX) nd_slot[t*B + b] = cnt++;
    else nd_slot[t*B + b] = -1;
  }
}

// ---------------- init: drawn-row samples for t=0 (fallback path only) ------
__global__ __launch_bounds__(256) void k_pre_argmax(
    const unsigned* __restrict__ kq, const unsigned char* __restrict__ draws,
    int* __restrict__ pre) {
  const int job  = blockIdx.x * 4 + (threadIdx.x >> 6);   // [0, B) at grid=B/4
  const int lane = threadIdx.x & 63;
  const int t = job >> 9, b = job & (B - 1);
  if (!draws[t*B + b]) { if (lane == 0) pre[job] = -1; return; }
  const unsigned g0 = kq[2*t], g1 = kq[2*t+1];
  unsigned best = 0u; int bv = V;
  for (int v = lane; v < V; v += 64) {
    unsigned bits = rbits(g0, g1, (unsigned)b, (unsigned)v) >> 9;
    if (bits > best || (bits == best && v < bv)) { best = bits; bv = v; }
  }
#pragma unroll
  for (int m = 1; m < 64; m <<= 1) {
    unsigned ob = __shfl_xor(best, m, 64);
    int      ov = __shfl_xor(bv,   m, 64);
    if (ob > best || (ob == best && ov < bv)) { best = ob; bv = ov; }
  }
  if (lane == 0) pre[job] = bv;
}

// ---------------- init: h=0, sample_prev=0, gh(0)=b_hh -----------------------
// gh(0) = 0 @ w_hh + b_hh: the frozen fmaf chain on h=0 accumulates exactly
// +0 (IEEE: +0 + (+/-0) = +0), so gh(0)[c] == b_hh[c] bit-exactly.
__global__ void k_init_state(float* __restrict__ h, int* __restrict__ samp,
                             float* __restrict__ gh,
                             const float* __restrict__ b_hh) {
  int b = blockIdx.x, tid = threadIdx.x;  // 256 threads
  h[b*H + tid] = 0.0f;
  h[b*H + 256 + tid] = 0.0f;
  if (tid == 0) samp[b] = 0;
#pragma unroll
  for (int i = 0; i < 6; i++) gh[(size_t)b*G3 + i*256 + tid] = b_hh[i*256 + tid];
}

// ---------------- init: w_out -> bf16 in MFMA-fragment-major layout ----------
__global__ void k_cast_w(const float* __restrict__ w,
                         unsigned short* __restrict__ w_sw) {
  int g = blockIdx.x*256 + threadIdx.x;   // [0, V*H/8)
  int v  = g >> 6;
  int k0 = (g & 63) * 8;
  const float* src = w + (size_t)v*H + k0;
  union { unsigned short s[8]; u32x4 vv; } u;
#pragma unroll
  for (int e = 0; e < 8; e++) u.s[e] = f2bf(src[e]);
  *(u32x4*)&w_sw[frag_off(v, k0, H/32)] = u.vv;
}

// ---------------- init: EG[v] = emb[v] @ w_ih^T + b_ih  (one-time) ----------
__global__ __launch_bounds__(512) void k_emb_gates(
    const float* __restrict__ emb, const float* __restrict__ w_ih,
    const float* __restrict__ b_ih, float* __restrict__ EG) {
  __shared__ __align__(16) float As[16][68];
  __shared__ __align__(16) float Ws[16][68];
  const int tid = threadIdx.x;             // 0..511
  const int tx = tid & 15, ty = tid >> 4;  // ty 0..31
  const int row0 = blockIdx.y * 64, col0 = blockIdx.x * 64;
  float acc[2][4] = {};
  for (int k0 = 0; k0 < E; k0 += 16) {
#pragma unroll
    for (int l = 0; l < 2; l++) {
      int idx = tid + l*512;
      int r = idx >> 4, kk = idx & 15;
      As[kk][r] = emb[(size_t)(row0 + r)*E + k0 + kk];
      Ws[kk][r] = w_ih[(size_t)(col0 + r)*E + k0 + kk];
    }
    __syncthreads();
#pragma unroll
    for (int kk = 0; kk < 16; kk++) {
      const float2 av = *(const float2*)&As[kk][ty*2];
      const float4 wv = *(const float4*)&Ws[kk][tx*4];
      const float a[2] = {av.x, av.y};
      const float w[4] = {wv.x, wv.y, wv.z, wv.w};
#pragma unroll
      for (int i = 0; i < 2; i++)
#pragma unroll
        for (int j = 0; j < 4; j++) acc[i][j] = fmaf(a[i], w[j], acc[i][j]);
    }
    __syncthreads();
  }
#pragma unroll
  for (int i = 0; i < 2; i++) {
    int r = row0 + ty*2 + i;
    int c = col0 + tx*4;
    float4 o;
    o.x = __fadd_rn(acc[i][0], b_ih[c + 0]);
    o.y = __fadd_rn(acc[i][1], b_ih[c + 1]);
    o.z = __fadd_rn(acc[i][2], b_ih[c + 2]);
    o.w = __fadd_rn(acc[i][3], b_ih[c + 3]);
    *(float4*)&EG[(size_t)r*G3 + c] = o;
  }
}

// ---------------- GRU math helpers (accumulation semantics FROZEN) ----------
__device__ __forceinline__ float sigm_acc(float v) {
  return (float)(1.0 / (1.0 + exp(-(double)v)));
}
__device__ __forceinline__ float tanh_acc(float v) {
  return (float)tanh((double)v);
}

// ============ K_FG: per-row [finish(t-1) -> GRU(t)] || pre(t) slab ==========
// Key fusion: samp[b] is consumed ONLY by row b's GRU, so block b computes
// finish(t-1) (verbatim body -> samp in shared) then, after __syncthreads,
// the GRU for row b. No cross-block dependency. Grid 1024:
//   bx < 512 : row b = bx (finish+GRU)
//   bx >= 512: pre(t) slab, row b = bx-512 (kq/draws only)
__global__ __launch_bounds__(256) void k_fingru(
    const float* __restrict__ EG, const float* __restrict__ gh,
    float* __restrict__ h, unsigned short* __restrict__ h_sw,
    const float* __restrict__ pmax, const float* __restrict__ psum,
    const float* __restrict__ plog,
    int* __restrict__ pre, const int* __restrict__ nd_slot,
    const float* __restrict__ nd_keys, const float* __restrict__ nd_kmax,
    const unsigned* __restrict__ kq, const unsigned char* __restrict__ draws,
    const float* __restrict__ w_out, const float* __restrict__ b_out,
    float* __restrict__ out_samples, float* __restrict__ out_lps,
    int* __restrict__ samp, int t) {
  const int tid = threadIdx.x;

  if (blockIdx.x >= 512) {
    // ================= pre-argmax slab for step t (bit-exact) ==============
    __shared__ unsigned sb[4];
    __shared__ int      sv[4];
    if (t >= S) return;
    const int b = blockIdx.x - 512;          // 0..511
    if (!draws[t*B + b]) { if (tid == 0) pre[t*B + b] = -1; return; }
    const unsigned g0 = kq[2*t], g1 = kq[2*t+1];
    unsigned best = 0u; int bv = V;
    for (int v = tid; v < V; v += 256) {
      unsigned bits = rbits(g0, g1, (unsigned)b, (unsigned)v) >> 9;
      if (bits > best || (bits == best && v < bv)) { best = bits; bv = v; }
    }
#pragma unroll
    for (int m = 1; m < 64; m <<= 1) {
      unsigned ob = __shfl_xor(best, m, 64);
      int      ov = __shfl_xor(bv,   m, 64);
      if (ob > best || (ob == best && ov < bv)) { best = ob; bv = ov; }
    }
    const int wv = tid >> 6;
    if ((tid & 63) == 0) { sb[wv] = best; sv[wv] = bv; }
    __syncthreads();
    if (tid == 0) {
      for (int i = 1; i < 4; i++) {
        unsigned ob = sb[i]; int ov = sv[i];
        if (ob > best || (ob == best && ov < bv)) { best = ob; bv = ov; }
      }
      pre[t*B + b] = bv;
    }
    return;
  }

  // ================= finish(t-1) for row b, then GRU(t) for row b ==========
  const int b = blockIdx.x;
  __shared__ float sA[256];
  __shared__ int   cand[160];
  __shared__ float cand_key[160], cand_lg[160];
  __shared__ int   ccnt;
  __shared__ int   s_samp;
  __shared__ float s_blog;

  const int tf = t - 1;
  if (tf >= 0) {
    const int* pre_t     = pre + tf*B;
    const int* nd_slot_t = nd_slot + tf*B;

    float m = -INFINITY;
    for (int c = tid; c < NCH; c += 256) m = fmaxf(m, pmax[b*NCH + c]);
    sA[tid] = m; __syncthreads();
    for (int s = 128; s > 0; s >>= 1) {
      if (tid < s) sA[tid] = fmaxf(sA[tid], sA[tid+s]);
      __syncthreads();
    }
    const float M = sA[0];
    __syncthreads();
    float sum = 0.0f;
    for (int c = tid; c < NCH; c += 256)
      sum += psum[b*NCH + c] * expf(pmax[b*NCH + c] - M);
    sA[tid] = sum; __syncthreads();
    for (int s = 128; s > 0; s >>= 1) {
      if (tid < s) sA[tid] += sA[tid+s];
      __syncthreads();
    }
    const float SUM = sA[0];
    __syncthreads();

    const int pr = pre_t[b];               // block-uniform
    if (pr >= 0) {
      if (tid == 0) { s_samp = pr; s_blog = plog[b]; }
    } else {
      const int slot = nd_slot_t[b];
      if (slot < 0) {                      // statistically impossible guard
        if (tid == 0) { s_samp = 0; s_blog = plog[b]; }
      } else {
        const unsigned g0 = kq[2*tf], g1 = kq[2*tf+1];
        if (tid == 0) ccnt = 0;
        float km = -INFINITY;
        for (int c = tid; c < NCH; c += 256) km = fmaxf(km, nd_kmax[slot*NCH + c]);
        sA[tid] = km; __syncthreads();
        for (int s = 128; s > 0; s >>= 1) {
          if (tid < s) sA[tid] = fmaxf(sA[tid], sA[tid+s]);
          __syncthreads();
        }
        const float thr = sA[0] - 0.0859375f;  // >= 2*(bf16 + fastlog err)
        __syncthreads();
        const float* keys = nd_keys + (size_t)slot*V;
        for (int c = tid; c < NCH; c += 256) {
          if (nd_kmax[slot*NCH + c] >= thr) {
            for (int j = 0; j < VBLK; j++) {
              float k = keys[c*VBLK + j];
              if (k >= thr) {
                int p = atomicAdd(&ccnt, 1);
                if (p < 160) cand[p] = c*VBLK + j;
              }
            }
          }
        }
        __syncthreads();
        const int nc = min(ccnt, 160);
        const int wid = tid >> 6, lane = tid & 63;
        for (int c = wid; c < nc; c += 4) {
          const int v = cand[c];
          const float* wr = w_out + (size_t)v*H;
          const float* hr = h + (size_t)b*H;
          float s = 0.0f;
#pragma unroll
          for (int i = 0; i < 8; i++) s = fmaf(hr[lane + 64*i], wr[lane + 64*i], s);
#pragma unroll
          for (int mm = 1; mm < 64; mm <<= 1) s += __shfl_xor(s, mm, 64);
          if (lane == 0) {
            float logit = __fadd_rn(s, b_out[v]);
            float key   = __fadd_rn(logit,
                            gumbel_exact(rbits(g0, g1, (unsigned)b, (unsigned)v)));
            cand_key[c] = key; cand_lg[c] = logit;
          }
        }
        __syncthreads();
        if (tid == 0) {
          float bk = -INFINITY; int bv = V; float bl = 0.0f;
          for (int c = 0; c < nc; c++) {
            float k = cand_key[c]; int v = cand[c];
            if (k > bk || (k == bk && v < bv)) { bk = k; bv = v; bl = cand_lg[c]; }
          }
          s_samp = bv; s_blog = bl;
        }
      }
    }
    __syncthreads();
    if (tid == 0) {
      const int sampled = s_samp;
      float lse = (float)log((double)SUM);
      float lp  = __fsub_rn(__fsub_rn(s_blog, M), lse);
      out_samples[b*S + tf] = (float)sampled;
      out_lps[b*S + tf]     = lp;
      samp[b] = sampled;
    }
    __syncthreads();                       // all h reads done; s_samp visible
  }

  if (t >= S) return;                      // trailing launch: finish only
  const int smp = (tf >= 0) ? s_samp : samp[b];   // samp init = 0 at t=0

  // ---- GRU for row b (math identical to the frozen k_gru_update) ----
  const float* gib = EG + (size_t)smp*G3;
  const float* ghb = gh + (size_t)b*G3;
#pragma unroll
  for (int e = 0; e < 2; e++) {
    const int j = tid*2 + e;
    float r  = sigm_acc(__fadd_rn(gib[j],     ghb[j]));
    float zz = sigm_acc(__fadd_rn(gib[H+j],   ghb[H+j]));
    float nn = tanh_acc(__fadd_rn(gib[2*H+j], __fmul_rn(r, ghb[2*H+j])));
    float hv = h[(size_t)b*H + j];
    float t1 = __fmul_rn(__fsub_rn(1.0f, zz), nn);
    float t2 = __fmul_rn(zz, hv);
    float hn = __fadd_rn(t1, t2);
    h[(size_t)b*H + j] = hn;
    h_sw[frag_off(b, j, H/32)] = f2bf(hn);
  }
}

// ===== K_C: logits tiles [bx<1024] || h-GEMM(t+1) slab [bx>=1024] ===========
// Tile path: R4-verified barrier-free direct-load MFMA GEMM, XCD-swizzled.
// Slab: R9-verified h-GEMM tiling computing gh(t+1) from h(t) -- h(t) is
// final (written by K_FG(t)); gh(t+1) has no reader until K_FG(t+1). Slab
// blocks launch last so they fill the logits tail. Fallback path launches
// grid=1024 (no slab; K_A provides gh).
__global__ __launch_bounds__(256) void k_mfma_logits(
    const unsigned short* __restrict__ h_sw,
    const unsigned short* __restrict__ w_sw,
    const float* __restrict__ b_out,
    const unsigned* __restrict__ kq,
    const int* __restrict__ pre_t,       // pre + t*B
    const int* __restrict__ nd_slot_t,   // nd_slot + t*B
    float* __restrict__ pmax, float* __restrict__ psum,
    float* __restrict__ plog,
    float* __restrict__ nd_keys, float* __restrict__ nd_kmax,
    const float* __restrict__ h, const float* __restrict__ w_hh,
    const float* __restrict__ b_hh, float* __restrict__ gh, int t) {
  const int tid  = threadIdx.x;
  __shared__ __align__(16) float As[2][16][68];
  __shared__ __align__(16) float Ws[2][16][52];

  if (blockIdx.x >= 1024) {
    // ================= h-GEMM slab: gh(t+1) from h(t) ======================
    const int sb = blockIdx.x - 1024;        // 0..255
    const int jw = tid & 15, rg = tid >> 4;
    const int j0 = (sb & 31) * 16;
    const int row0 = (sb >> 5) * 64;
    float ah[4][3] = {};
    float pa[4], pw[3];
#pragma unroll
    for (int l = 0; l < 4; l++) {
      int idx = tid + l*256;
      pa[l] = h[(size_t)(row0 + (idx >> 4))*H + (idx & 15)];
    }
#pragma unroll
    for (int l = 0; l < 3; l++) {
      int idx = tid + l*256;
      int c = idx >> 4;
      pw[l] = w_hh[(size_t)((c >> 4)*512 + j0 + (c & 15))*H + (idx & 15)];
    }
#pragma unroll
    for (int l = 0; l < 4; l++) {
      int idx = tid + l*256;
      As[0][idx & 15][idx >> 4] = pa[l];
    }
#pragma unroll
    for (int l = 0; l < 3; l++) {
      int idx = tid + l*256;
      Ws[0][idx & 15][idx >> 4] = pw[l];
    }
    __syncthreads();
    int p = 0;
#pragma unroll 1
    for (int tile = 0; tile < 32; tile++) {
      if (tile < 31) {
        const int k0 = (tile + 1) * 16;
#pragma unroll
        for (int l = 0; l < 4; l++) {
          int idx = tid + l*256;
          pa[l] = h[(size_t)(row0 + (idx >> 4))*H + k0 + (idx & 15)];
        }
#pragma unroll
        for (int l = 0; l < 3; l++) {
          int idx = tid + l*256;
          int c = idx >> 4;
          pw[l] = w_hh[(size_t)((c >> 4)*512 + j0 + (c & 15))*H + k0 + (idx & 15)];
        }
      }
#pragma unroll
      for (int kk = 0; kk < 16; kk++) {
        const float4 av = *(const float4*)&As[p][kk][rg*4];
        const float a[4] = {av.x, av.y, av.z, av.w};
        const float w0 = Ws[p][kk][jw];
        const float w1 = Ws[p][kk][16 + jw];
        const float w2 = Ws[p][kk][32 + jw];
#pragma unroll
        for (int i = 0; i < 4; i++) {
          ah[i][0] = fmaf(a[i], w0, ah[i][0]);
          ah[i][1] = fmaf(a[i], w1, ah[i][1]);
          ah[i][2] = fmaf(a[i], w2, ah[i][2]);
        }
      }
      if (tile < 31) {
#pragma unroll
        for (int l = 0; l < 4; l++) {
          int idx = tid + l*256;
          As[p ^ 1][idx & 15][idx >> 4] = pa[l];
        }
#pragma unroll
        for (int l = 0; l < 3; l++) {
          int idx = tid + l*256;
          Ws[p ^ 1][idx & 15][idx >> 4] = pw[l];
        }
        __syncthreads();
        p ^= 1;
      }
    }
    const int j = j0 + jw;
    const float bh_r = b_hh[j], bh_z = b_hh[512 + j], bh_n = b_hh[1024 + j];
#pragma unroll
    for (int i = 0; i < 4; i++) {
      const int b = row0 + rg*4 + i;
      gh[(size_t)b*G3 +        j] = __fadd_rn(ah[i][0], bh_r);
      gh[(size_t)b*G3 +  512 + j] = __fadd_rn(ah[i][1], bh_z);
      gh[(size_t)b*G3 + 1024 + j] = __fadd_rn(ah[i][2], bh_n);
    }
    return;
  }

  // ---- GEMM tiles: XCD-chunked bijective swizzle over 1024 slots ----
  const int L  = blockIdx.x;                           // 0..1023
  const int wg = (L & 7) * 128 + (L >> 3);             // 128 contiguous wg/XCD
  if (wg >= 2*NCH) return;                             // 24 idle slots
  const int vblk = wg >> 1;      // 0..499; 64 contiguous vblk per XCD = 4 MB
  const int bblk = wg & 1;       // both b-halves of a vblk on the same XCD
  const int lane = tid & 63, w = tid >> 6;
  const int quad = lane >> 4, l15 = lane & 15;

  f32x4 acc[4][4] = {};

  const int mtBase = bblk*16 + w*4;   // h rowTile base for this wave
  const int ntBase = vblk*4;          // w rowTile base
  const unsigned short* hp = h_sw + (size_t)mtBase*16*512 + lane*8;
  const unsigned short* wp = w_sw + (size_t)ntBase*16*512 + lane*8;

  // prologue: load kt=0 fragments for A and B
  bf16x8 afc[4], bfc[4];
#pragma unroll
  for (int mt = 0; mt < 4; mt++)
    afc[mt] = __builtin_bit_cast(bf16x8, *(const u32x4*)(hp + (size_t)(mt*16)*512));
#pragma unroll
  for (int nt = 0; nt < 4; nt++)
    bfc[nt] = __builtin_bit_cast(bf16x8, *(const u32x4*)(wp + (size_t)(nt*16)*512));

#pragma unroll 1
  for (int kt = 0; kt < 15; kt++) {
    bf16x8 afn[4], bfn[4];
#pragma unroll
    for (int mt = 0; mt < 4; mt++)
      afn[mt] = __builtin_bit_cast(bf16x8,
          *(const u32x4*)(hp + (size_t)(mt*16 + kt + 1)*512));
#pragma unroll
    for (int nt = 0; nt < 4; nt++)
      bfn[nt] = __builtin_bit_cast(bf16x8,
          *(const u32x4*)(wp + (size_t)(nt*16 + kt + 1)*512));
#pragma unroll
    for (int mt = 0; mt < 4; mt++)
#pragma unroll
      for (int nt = 0; nt < 4; nt++)
        acc[mt][nt] = __builtin_amdgcn_mfma_f32_16x16x32_bf16(
            afc[mt], bfc[nt], acc[mt][nt], 0, 0, 0);
#pragma unroll
    for (int mt = 0; mt < 4; mt++) afc[mt] = afn[mt];
#pragma unroll
    for (int nt = 0; nt < 4; nt++) bfc[nt] = bfn[nt];
  }
  {  // kt = 15
#pragma unroll
    for (int mt = 0; mt < 4; mt++)
#pragma unroll
      for (int nt = 0; nt < 4; nt++)
        acc[mt][nt] = __builtin_amdgcn_mfma_f32_16x16x32_bf16(
            afc[mt], bfc[nt], acc[mt][nt], 0, 0, 0);
  }

  // epilogue: lane holds D[b = bW + mt*16 + quad*4 + r][v = vW + nt*16 + l15]
  const int bW = bblk*256 + w*64;
  const int vW = vblk*64;
  const unsigned g0 = kq[2*t], g1 = kq[2*t+1];
  float bias[4];
#pragma unroll
  for (int nt = 0; nt < 4; nt++) bias[nt] = b_out[vW + nt*16 + l15];

#pragma unroll
  for (int mt = 0; mt < 4; mt++) {
#pragma unroll
    for (int r = 0; r < 4; r++) {
      const int b = bW + mt*16 + quad*4 + r;
      float lg[4];
#pragma unroll
      for (int nt = 0; nt < 4; nt++) lg[nt] = acc[mt][nt][r] + bias[nt];
      float lmax = fmaxf(fmaxf(lg[0], lg[1]), fmaxf(lg[2], lg[3]));
#pragma unroll
      for (int m = 1; m < 16; m <<= 1) lmax = fmaxf(lmax, __shfl_xor(lmax, m, 64));
      float ls = 0.0f;
#pragma unroll
      for (int nt = 0; nt < 4; nt++) ls += __expf(lg[nt] - lmax);
#pragma unroll
      for (int m = 1; m < 16; m <<= 1) ls += __shfl_xor(ls, m, 64);
      if (l15 == 0) { pmax[b*NCH + vblk] = lmax; psum[b*NCH + vblk] = ls; }
      const int pr = pre_t[b];
      if (pr >= 0) {
        int rel = pr - vW;
        if (rel >= 0 && rel < 64 && (rel & 15) == l15) plog[b] = lg[rel >> 4];
      } else {
        const int slot = nd_slot_t[b];
        if (slot >= 0) {
          float key[4];
#pragma unroll
          for (int nt = 0; nt < 4; nt++)
            key[nt] = lg[nt] + gumbel_fast(
                rbits(g0, g1, (unsigned)b, (unsigned)(vW + nt*16 + l15)));
          float* dst = nd_keys + (size_t)slot*V + vW + l15;
#pragma unroll
          for (int nt = 0; nt < 4; nt++) dst[nt*16] = key[nt];
          float kmx = fmaxf(fmaxf(key[0], key[1]), fmaxf(key[2], key[3]));
#pragma unroll
          for (int m = 1; m < 16; m <<= 1) kmx = fmaxf(kmx, __shfl_xor(kmx, m, 64));
          if (l15 == 0) nd_kmax[slot*NCH + vblk] = kmx;
        }
      }
    }
  }
}

// =================== fallback path (EG doesn't fit): R9 kernels =============
__global__ __launch_bounds__(256) void k_gates_finish(
    const float* __restrict__ h, const float* __restrict__ w_hh,
    const float* __restrict__ b_hh, float* __restrict__ gh,
    const float* __restrict__ pmax, const float* __restrict__ psum,
    const float* __restrict__ plog,
    int* __restrict__ pre, const int* __restrict__ nd_slot,
    const float* __restrict__ nd_keys, const float* __restrict__ nd_kmax,
    const unsigned* __restrict__ kq, const unsigned char* __restrict__ draws,
    const float* __restrict__ w_out, const float* __restrict__ b_out,
    float* __restrict__ out_samples, float* __restrict__ out_lps,
    int* __restrict__ samp, int t) {
  const int tid = threadIdx.x;
  union Sh {
    struct { float As[2][16][68]; float Ws[2][16][52]; } g;
    struct { float sA[256]; int cand[160]; float ck[160]; float cl[160];
             int ccnt; int samp; float blog; } f;
    struct { unsigned sb[4]; int sv[4]; } p;
  };
  __shared__ Sh sh;

  if (blockIdx.x < 256) {
    if (t >= S) return;
    const int jw = tid & 15, rg = tid >> 4;
    const int j0 = (blockIdx.x & 31) * 16;
    const int row0 = (blockIdx.x >> 5) * 64;
    float ah[4][3] = {};
    float pa[4], pw[3];
#pragma unroll
    for (int l = 0; l < 4; l++) {
      int idx = tid + l*256;
      pa[l] = h[(size_t)(row0 + (idx >> 4))*H + (idx & 15)];
    }
#pragma unroll
    for (int l = 0; l < 3; l++) {
      int idx = tid + l*256;
      int c = idx >> 4;
      pw[l] = w_hh[(size_t)((c >> 4)*512 + j0 + (c & 15))*H + (idx & 15)];
    }
#pragma unroll
    for (int l = 0; l < 4; l++) {
      int idx = tid + l*256;
      sh.g.As[0][idx & 15][idx >> 4] = pa[l];
    }
#pragma unroll
    for (int l = 0; l < 3; l++) {
      int idx = tid + l*256;
      sh.g.Ws[0][idx & 15][idx >> 4] = pw[l];
    }
    __syncthreads();
    int p = 0;
#pragma unroll 1
    for (int tile = 0; tile < 32; tile++) {
      if (tile < 31) {
        const int k0 = (tile + 1) * 16;
#pragma unroll
        for (int l = 0; l < 4; l++) {
          int idx = tid + l*256;
          pa[l] = h[(size_t)(row0 + (idx >> 4))*H + k0 + (idx & 15)];
        }
#pragma unroll
        for (int l = 0; l < 3; l++) {
          int idx = tid + l*256;
          int c = idx >> 4;
          pw[l] = w_hh[(size_t)((c >> 4)*512 + j0 + (c & 15))*H + k0 + (idx & 15)];
        }
      }
#pragma unroll
      for (int kk = 0; kk < 16; kk++) {
        const float4 av = *(const float4*)&sh.g.As[p][kk][rg*4];
        const float a[4] = {av.x, av.y, av.z, av.w};
        const float w0 = sh.g.Ws[p][kk][jw];
        const float w1 = sh.g.Ws[p][kk][16 + jw];
        const float w2 = sh.g.Ws[p][kk][32 + jw];
#pragma unroll
        for (int i = 0; i < 4; i++) {
          ah[i][0] = fmaf(a[i], w0, ah[i][0]);
          ah[i][1] = fmaf(a[i], w1, ah[i][1]);
          ah[i][2] = fmaf(a[i], w2, ah[i][2]);
        }
      }
      if (tile < 31) {
#pragma unroll
        for (int l = 0; l < 4; l++) {
          int idx = tid + l*256;
          sh.g.As[p ^ 1][idx & 15][idx >> 4] = pa[l];
        }
#pragma unroll
        for (int l = 0; l < 3; l++) {
          int idx = tid + l*256;
          sh.g.Ws[p ^ 1][idx & 15][idx >> 4] = pw[l];
        }
        __syncthreads();
        p ^= 1;
      }
    }
    const int j = j0 + jw;
    const float bh_r = b_hh[j], bh_z = b_hh[512 + j], bh_n = b_hh[1024 + j];
#pragma unroll
    for (int i = 0; i < 4; i++) {
      const int b = row0 + rg*4 + i;
      gh[(size_t)b*G3 +        j] = __fadd_rn(ah[i][0], bh_r);
      gh[(size_t)b*G3 +  512 + j] = __fadd_rn(ah[i][1], bh_z);
      gh[(size_t)b*G3 + 1024 + j] = __fadd_rn(ah[i][2], bh_n);
    }
    return;
  }

  if (blockIdx.x >= 768) {
    const int tn = t + 1;
    if (tn >= S) return;
    const int b = blockIdx.x - 768;
    if (!draws[tn*B + b]) { if (tid == 0) pre[tn*B + b] = -1; return; }
    const unsigned g0 = kq[2*tn], g1 = kq[2*tn+1];
    unsigned best = 0u; int bv = V;
    for (int v = tid; v < V; v += 256) {
      unsigned bits = rbits(g0, g1, (unsigned)b, (unsigned)v) >> 9;
      if (bits > best || (bits == best && v < bv)) { best = bits; bv = v; }
    }
#pragma unroll
    for (int m = 1; m < 64; m <<= 1) {
      unsigned ob = __shfl_xor(best, m, 64);
      int      ov = __shfl_xor(bv,   m, 64);
      if (ob > best || (ob == best && ov < bv)) { best = ob; bv = ov; }
    }
    const int wv = tid >> 6;
    if ((tid & 63) == 0) { sh.p.sb[wv] = best; sh.p.sv[wv] = bv; }
    __syncthreads();
    if (tid == 0) {
      for (int i = 1; i < 4; i++) {
        unsigned ob = sh.p.sb[i]; int ov = sh.p.sv[i];
        if (ob > best || (ob == best && ov < bv)) { best = ob; bv = ov; }
      }
      pre[tn*B + b] = bv;
    }
    return;
  }

  const int tf = t - 1;
  if (tf < 0) return;
  const int b = blockIdx.x - 256;
  const int* pre_t     = pre + tf*B;
  const int* nd_slot_t = nd_slot + tf*B;

  float m = -INFINITY;
  for (int c = tid; c < NCH; c += 256) m = fmaxf(m, pmax[b*NCH + c]);
  sh.f.sA[tid] = m; __syncthreads();
  for (int s = 128; s > 0; s >>= 1) {
    if (tid < s) sh.f.sA[tid] = fmaxf(sh.f.sA[tid], sh.f.sA[tid+s]);
    __syncthreads();
  }
  const float M = sh.f.sA[0];
  __syncthreads();
  float sum = 0.0f;
  for (int c = tid; c < NCH; c += 256)
    sum += psum[b*NCH + c] * expf(pmax[b*NCH + c] - M);
  sh.f.sA[tid] = sum; __syncthreads();
  for (int s = 128; s > 0; s >>= 1) {
    if (tid < s) sh.f.sA[tid] += sh.f.sA[tid+s];
    __syncthreads();
  }
  const float SUM = sh.f.sA[0];
  __syncthreads();

  const int pr = pre_t[b];
  if (pr >= 0) {
    if (tid == 0) { sh.f.samp = pr; sh.f.blog = plog[b]; }
  } else {
    const int slot = nd_slot_t[b];
    if (slot < 0) {
      if (tid == 0) { sh.f.samp = 0; sh.f.blog = plog[b]; }
    } else {
      const unsigned g0 = kq[2*tf], g1 = kq[2*tf+1];
      if (tid == 0) sh.f.ccnt = 0;
      float km = -INFINITY;
      for (int c = tid; c < NCH; c += 256) km = fmaxf(km, nd_kmax[slot*NCH + c]);
      sh.f.sA[tid] = km; __syncthreads();
      for (int s = 128; s > 0; s >>= 1) {
        if (tid < s) sh.f.sA[tid] = fmaxf(sh.f.sA[tid], sh.f.sA[tid+s]);
        __syncthreads();
      }
      const float thr = sh.f.sA[0] - 0.0859375f;
      __syncthreads();
      const float* keys = nd_keys + (size_t)slot*V;
      for (int c = tid; c < NCH; c += 256) {
        if (nd_kmax[slot*NCH + c] >= thr) {
          for (int j = 0; j < VBLK; j++) {
            float k = keys[c*VBLK + j];
            if (k >= thr) {
              int p = atomicAdd(&sh.f.ccnt, 1);
              if (p < 160) sh.f.cand[p] = c*VBLK + j;
            }
          }
        }
      }
      __syncthreads();
      const int nc = min(sh.f.ccnt, 160);
      const int wid = tid >> 6, lane = tid & 63;
      for (int c = wid; c < nc; c += 4) {
        const int v = sh.f.cand[c];
        const float* wr = w_out + (size_t)v*H;
        const float* hr = h + (size_t)b*H;
        float s = 0.0f;
#pragma unroll
        for (int i = 0; i < 8; i++) s = fmaf(hr[lane + 64*i], wr[lane + 64*i], s);
#pragma unroll
        for (int mm = 1; mm < 64; mm <<= 1) s += __shfl_xor(s, mm, 64);
        if (lane == 0) {
          float logit = __fadd_rn(s, b_out[v]);
          float key   = __fadd_rn(logit,
                          gumbel_exact(rbits(g0, g1, (unsigned)b, (unsigned)v)));
          sh.f.ck[c] = key; sh.f.cl[c] = logit;
        }
      }
      __syncthreads();
      if (tid == 0) {
        float bk = -INFINITY; int bv = V; float bl = 0.0f;
        for (int c = 0; c < nc; c++) {
          float k = sh.f.ck[c]; int v = sh.f.cand[c];
          if (k > bk || (k == bk && v < bv)) { bk = k; bv = v; bl = sh.f.cl[c]; }
        }
        sh.f.samp = bv; sh.f.blog = bl;
      }
    }
  }
  __syncthreads();
  if (tid == 0) {
    const int sampled = sh.f.samp;
    float lse = (float)log((double)SUM);
    float lp  = __fsub_rn(__fsub_rn(sh.f.blog, M), lse);
    out_samples[b*S + tf] = (float)sampled;
    out_lps[b*S + tf]     = lp;
    samp[b] = sampled;
  }
}

__global__ __launch_bounds__(256) void k_xgru(
    const float* __restrict__ emb, const int* __restrict__ samp,
    const float* __restrict__ w_ih, const float* __restrict__ b_ih,
    const float* __restrict__ gh, float* __restrict__ h,
    unsigned short* __restrict__ h_sw) {
  __shared__ __align__(16) float As[2][16][68];
  __shared__ __align__(16) float Ws[2][16][52];
  __shared__ int srow[64];
  const int tid = threadIdx.x;
  const int jw = tid & 15, rg = tid >> 4;
  const int j0 = blockIdx.x * 16;
  const int row0 = blockIdx.y * 64;
  if (tid < 64) srow[tid] = samp[row0 + tid];
  __syncthreads();

  float ai[4][3] = {};
  float pa[4], pw[3];
#pragma unroll
  for (int l = 0; l < 4; l++) {
    int idx = tid + l*256;
    pa[l] = emb[(size_t)srow[idx >> 4]*E + (idx & 15)];
  }
#pragma unroll
  for (int l = 0; l < 3; l++) {
    int idx = tid + l*256;
    int c = idx >> 4;
    pw[l] = w_ih[(size_t)((c >> 4)*512 + j0 + (c & 15))*E + (idx & 15)];
  }
#pragma unroll
  for (int l = 0; l < 4; l++) {
    int idx = tid + l*256;
    As[0][idx & 15][idx >> 4] = pa[l];
  }
#pragma unroll
  for (int l = 0; l < 3; l++) {
    int idx = tid + l*256;
    Ws[0][idx & 15][idx >> 4] = pw[l];
  }
  __syncthreads();
  int p = 0;
#pragma unroll 1
  for (int tile = 0; tile < 16; tile++) {
    if (tile < 15) {
      const int k0 = (tile + 1) * 16;
#pragma unroll
      for (int l = 0; l < 4; l++) {
        int idx = tid + l*256;
        pa[l] = emb[(size_t)srow[idx >> 4]*E + k0 + (idx & 15)];
      }
#pragma unroll
      for (int l = 0; l < 3; l++) {
        int idx = tid + l*256;
        int c = idx >> 4;
        pw[l] = w_ih[(size_t)((c >> 4)*512 + j0 + (c & 15))*E + k0 + (idx & 15)];
      }
    }
#pragma unroll
    for (int kk = 0; kk < 16; kk++) {
      const float4 av = *(const float4*)&As[p][kk][rg*4];
      const float a[4] = {av.x, av.y, av.z, av.w};
      const float w0 = Ws[p][kk][jw];
      const float w1 = Ws[p][kk][16 + jw];
      const float w2 = Ws[p][kk][32 + jw];
#pragma unroll
      for (int i = 0; i < 4; i++) {
        ai[i][0] = fmaf(a[i], w0, ai[i][0]);
        ai[i][1] = fmaf(a[i], w1, ai[i][1]);
        ai[i][2] = fmaf(a[i], w2, ai[i][2]);
      }
    }
    if (tile < 15) {
#pragma unroll
      for (int l = 0; l < 4; l++) {
        int idx = tid + l*256;
        As[p ^ 1][idx & 15][idx >> 4] = pa[l];
      }
#pragma unroll
      for (int l = 0; l < 3; l++) {
        int idx = tid + l*256;
        Ws[p ^ 1][idx & 15][idx >> 4] = pw[l];
      }
      __syncthreads();
      p ^= 1;
    }
  }

  const int j = j0 + jw;
  const float bi_r = b_ih[j], bi_z = b_ih[512 + j], bi_n = b_ih[1024 + j];
#pragma unroll
  for (int i = 0; i < 4; i++) {
    const int b = row0 + rg*4 + i;
    float gi_r = __fadd_rn(ai[i][0], bi_r);
    float gi_z = __fadd_rn(ai[i][1], bi_z);
    float gi_n = __fadd_rn(ai[i][2], bi_n);
    float gh_r = gh[(size_t)b*G3 + j];
    float gh_z = gh[(size_t)b*G3 + 512 + j];
    float gh_n = gh[(size_t)b*G3 + 1024 + j];
    float r  = sigm_acc(__fadd_rn(gi_r, gh_r));
    float zz = sigm_acc(__fadd_rn(gi_z, gh_z));
    float nn = tanh_acc(__fadd_rn(gi_n, __fmul_rn(r, gh_n)));
    float hv = h[(size_t)b*H + j];
    float t1 = __fmul_rn(__fsub_rn(1.0f, zz), nn);
    float t2 = __fmul_rn(zz, hv);
    float hn = __fadd_rn(t1, t2);
    h[(size_t)b*H + j] = hn;
    h_sw[frag_off(b, j, H/32)] = f2bf(hn);
  }
}

} // namespace

extern "C" void kernel_launch(void* const* d_in, const int* in_sizes, int n_in,
                              void* d_out, int out_size, void* d_ws, size_t ws_size,
                              hipStream_t stream) {
  (void)in_sizes; (void)n_in; (void)out_size;
  const float* emb   = (const float*)d_in[0];
  const float* w_ih  = (const float*)d_in[1];
  const float* w_hh  = (const float*)d_in[2];
  const float* b_ih  = (const float*)d_in[3];
  const float* b_hh  = (const float*)d_in[4];
  const float* w_out = (const float*)d_in[5];
  const float* b_out = (const float*)d_in[6];
  float* out = (float*)d_out;

  char* wsb = (char*)d_ws;
  size_t off = 0;
  auto alloc = [&](size_t nbytes) {
    char* p = wsb + off;
    off += (nbytes + 255) & ~size_t(255);
    return p;
  };
  float* h     = (float*)alloc((size_t)B*H*4);
  float* gh    = (float*)alloc((size_t)B*G3*4);
  unsigned short* h_sw = (unsigned short*)alloc((size_t)B*H*2);
  unsigned short* w_sw = (unsigned short*)alloc((size_t)V*H*2);
  float* pmax  = (float*)alloc((size_t)B*NCH*4);
  float* psum  = (float*)alloc((size_t)B*NCH*4);
  float* plog  = (float*)alloc((size_t)B*4);
  unsigned* kq = (unsigned*)alloc((size_t)S*2*4);
  unsigned* ke = (unsigned*)alloc((size_t)S*2*4);
  unsigned char* draws = (unsigned char*)alloc((size_t)S*B);
  int* pre     = (int*)alloc((size_t)S*B*4);
  int* nd_slot = (int*)alloc((size_t)S*B*4);
  float* nd_keys = (float*)alloc((size_t)NDMAX*V*4);
  float* nd_kmax = (float*)alloc((size_t)NDMAX*NCH*4);
  int* samp    = (int*)alloc((size_t)B*4);
  if (off > ws_size) {
    fprintf(stderr, "kernel_launch: workspace too small (need %zu, have %zu)\n",
            off, ws_size);
    return;
  }
  // EG (196.6 MB) allocated last; fall back to the R9 3-kernel flow if it
  // doesn't fit.
  const size_t eg_bytes = ((size_t)V*G3*4 + 255) & ~size_t(255);
  const bool use_eg = (off + eg_bytes <= ws_size);
  float* EG = use_eg ? (float*)alloc(eg_bytes) : nullptr;

  k_init_rng<<<1, S, 0, stream>>>(kq, ke);
  k_init_draws<<<S, B, 0, stream>>>(ke, draws);
  k_init_nd<<<S, 64, 0, stream>>>(draws, nd_slot);
  k_init_state<<<B, 256, 0, stream>>>(h, samp, gh, b_hh);
  k_cast_w<<<(V*H/8)/256, 256, 0, stream>>>(w_out, w_sw);

  if (use_eg) {
    // ======== fast path: 2 launches/step ========
    k_emb_gates<<<dim3(G3/64, V/64), 512, 0, stream>>>(emb, w_ih, b_ih, EG);
    for (int t = 0; t < S; t++) {
      k_fingru<<<1024, 256, 0, stream>>>(
          EG, gh, h, h_sw, pmax, psum, plog, pre, nd_slot,
          nd_keys, nd_kmax, kq, draws, w_out, b_out,
          out, out + (size_t)B*S, samp, t);
      k_mfma_logits<<<1280, 256, 0, stream>>>(
          h_sw, w_sw, b_out, kq, pre + t*B, nd_slot + t*B,
          pmax, psum, plog, nd_keys, nd_kmax, h, w_hh, b_hh, gh, t);
    }
    // trailing finish for t = S-1 (GRU and pre slabs self-disable at t >= S)
    k_fingru<<<1024, 256, 0, stream>>>(
        EG, gh, h, h_sw, pmax, psum, plog, pre, nd_slot,
        nd_keys, nd_kmax, kq, draws, w_out, b_out,
        out, out + (size_t)B*S, samp, S);
  } else {
    // ======== fallback: verified R9 3-kernel flow ========
    k_pre_argmax<<<B/4, 256, 0, stream>>>(kq, draws, pre);   // t=0 only
    for (int t = 0; t < S; t++) {
      k_gates_finish<<<1280, 256, 0, stream>>>(
          h, w_hh, b_hh, gh, pmax, psum, plog, pre, nd_slot,
          nd_keys, nd_kmax, kq, draws, w_out, b_out,
          out, out + (size_t)B*S, samp, t);
      k_xgru<<<dim3(32, 8), 256, 0, stream>>>(emb, samp, w_ih, b_ih,
                                              gh, h, h_sw);
      k_mfma_logits<<<1024, 256, 0, stream>>>(
          h_sw, w_sw, b_out, kq, pre + t*B, nd_slot + t*B,
          pmax, psum, plog, nd_keys, nd_kmax, h, w_hh, b_hh, gh, t);
    }
    k_gates_finish<<<1280, 256, 0, stream>>>(
        h, w_hh, b_hh, gh, pmax, psum, plog, pre, nd_slot,
        nd_keys, nd_kmax, kq, draws, w_out, b_out,
        out, out + (size_t)B*S, samp, S);
  }
}